// Round 12
// baseline (480.699 us; speedup 1.0000x reference)
//
#include <hip/hip_runtime.h>

typedef unsigned short u16;
typedef unsigned int u32;
typedef __attribute__((ext_vector_type(8))) short short8_t;  // 8 bf16 (4 VGPRs)
typedef __attribute__((ext_vector_type(4))) float f32x4;

static constexpr int Bc = 4, Sc = 1024, Hc = 32, HKVc = 8, Dc = 128;
static constexpr int BS = Bc * Sc;     // 4096 rows
static constexpr int DIMc = 4096;

__device__ __forceinline__ u16 f2bf(float f) {
  u32 u = __float_as_uint(f);
  u32 r = (u + 0x7fffu + ((u >> 16) & 1u)) >> 16;  // RNE
  return (u16)r;
}
__device__ __forceinline__ float bf2f(u16 u) {
  return __uint_as_float(((u32)u) << 16);
}
__device__ __forceinline__ void gload_lds16(const void* g, void* l) {
  __builtin_amdgcn_global_load_lds((const __attribute__((address_space(1))) void*)g,
                                   (__attribute__((address_space(3))) void*)l, 16, 0, 0);
}

#define SBAR __builtin_amdgcn_sched_barrier(0)
#define PBARRIER do { SBAR; __builtin_amdgcn_s_barrier(); SBAR; } while (0)
#define WAITVM(N) asm volatile("s_waitcnt vmcnt(" #N ")" ::: "memory")

// ---------------- RoPE table: cos/sin for (s, i) ----------------
__global__ void rope_table_k(float* __restrict__ tbl) {
  int i = blockIdx.x * 256 + threadIdx.x;     // 1024*64
  int s = i >> 6, fi = i & 63;
  float freq = powf(10000.f, -(float)fi / 64.f);
  float ang = (float)s * freq;
  float sv, cv;
  sincosf(ang, &sv, &cv);
  tbl[2 * i] = cv;
  tbl[2 * i + 1] = sv;
}

// ---------------- fp32 -> bf16 convert (vectorized) ----------------
__global__ void f32_to_bf16_k(const float* __restrict__ in, u16* __restrict__ out, int n4) {
  int i = blockIdx.x * 256 + threadIdx.x;
  if (i >= n4) return;
  float4 v = *(const float4*)(in + (size_t)i * 4);
  uint2 pk;
  pk.x = (u32)f2bf(v.x) | ((u32)f2bf(v.y) << 16);
  pk.y = (u32)f2bf(v.z) | ((u32)f2bf(v.w) << 16);
  *(uint2*)(out + (size_t)i * 4) = pk;
}

// ---------------- W (K,N) fp32 -> WT (N,K) bf16, tiled transpose ----------------
__global__ __launch_bounds__(256) void transpose_w_k(const float* __restrict__ W, u16* __restrict__ WT,
                                                     int Kdim, int Ndim) {
  __shared__ float tile[64 * 65];
  const int t = threadIdx.x;
  const int n0 = blockIdx.x * 64, k0 = blockIdx.y * 64;
  #pragma unroll
  for (int p = 0; p < 4; ++p) {
    int idx = p * 256 + t;           // 1024 float4 chunks
    int r = idx >> 4, c = (idx & 15) * 4;
    float4 v = *(const float4*)(W + (size_t)(k0 + r) * Ndim + n0 + c);
    tile[r * 65 + c + 0] = v.x;
    tile[r * 65 + c + 1] = v.y;
    tile[r * 65 + c + 2] = v.z;
    tile[r * 65 + c + 3] = v.w;
  }
  __syncthreads();
  #pragma unroll
  for (int p = 0; p < 2; ++p) {
    int idx = p * 256 + t;           // 512 chunks of 8 bf16
    int n = idx >> 3, c = (idx & 7) * 8;
    alignas(16) u16 o[8];
    #pragma unroll
    for (int i = 0; i < 8; ++i) o[i] = f2bf(tile[(c + i) * 65 + n]);
    *(uint4*)(WT + (size_t)(n0 + n) * Kdim + k0 + c) = *(const uint4*)o;
  }
}

// ---------------- 256^2-tile GEMM, 8-phase (m201-style) schedule ----------------
// MODE 1: f32 C row-major; MODE 2: bf16 + fused RoPE + relayout to Q[b][h][s][d].
// Per K-tile: 4 sub-phases, each {ds-reads + stage -> barrier -> 16 MFMA
// (setprio-wrapped) -> barrier}. Each fragment read once (12/8/4/0 reads per
// phase). Stages target tile T+2 into cb regions whose last reader completed
// before the previous phase's 2nd barrier. vmcnt(8) once per tile at ph4
// (retires T+1's 8 loads; T+2's 8 remain in flight) — never drains to 0 in
// steady state.
#define MFMAQ(QI, AF, BF)                                                                \
  do {                                                                                   \
    __builtin_amdgcn_s_setprio(1);                                                       \
    _Pragma("unroll") for (int mf = 0; mf < 4; ++mf)                                     \
      _Pragma("unroll") for (int nf = 0; nf < 2; ++nf)                                   \
        _Pragma("unroll") for (int kk = 0; kk < 2; ++kk)                                 \
          acc[QI][mf][nf] = __builtin_amdgcn_mfma_f32_16x16x32_bf16(                     \
              AF[mf][kk], BF[nf][kk], acc[QI][mf][nf], 0, 0, 0);                         \
    __builtin_amdgcn_s_setprio(0);                                                       \
  } while (0)

template <int MODE>
__global__ __launch_bounds__(512, 2) void gemm256(const u16* __restrict__ A, const u16* __restrict__ BT,
                                                  void* __restrict__ Cv, const float* __restrict__ tbl,
                                                  int M, int N, int K) {
  extern __shared__ char smem[];   // 131072 B
  const int t = threadIdx.x, l = t & 63, w = t >> 6;
  const int ln15 = l & 15, lh = l >> 4;
  const int NT = K >> 6;

  int id = blockIdx.x;
  int nwg = gridDim.x;
  int swz = ((nwg & 7) == 0) ? ((id & 7) * (nwg >> 3) + (id >> 3)) : id;
  const int nbn = N >> 8;
  const int bm = swz / nbn, bn = swz % nbn;

  const u16* Ag = A + (size_t)bm * 256 * K;
  const u16* Bg = BT + (size_t)bn * 256 * K;

  f32x4 acc[4][4][2];
  #pragma unroll
  for (int q = 0; q < 4; ++q)
    #pragma unroll
    for (int mf = 0; mf < 4; ++mf)
      #pragma unroll
      for (int nf = 0; nf < 2; ++nf) acc[q][mf][nf] = f32x4{0.f, 0.f, 0.f, 0.f};
  short8_t af[4][2], af2[4][2], bfB0[2][2], bfB1[2][2];

  const int srow = (l >> 3);
  const int sck  = (l & 7) ^ srow;
  auto stageA = [&](char* bufbase, int h, int tt) {
    char* lb = bufbase + h * 16384 + w * 1024;
    const u16* g = Ag + (size_t)(h * 128 + w * 8 + srow) * K + tt * 64 + (sck << 3);
    gload_lds16(g, lb);
    gload_lds16(g + (size_t)64 * K, lb + 8192);
  };
  auto stageB = [&](char* bufbase, int h, int tt) {
    char* lb = bufbase + 32768 + h * 16384 + w * 1024;
    const u16* g = Bg + (size_t)(h * 128 + w * 8 + srow) * K + tt * 64 + (sck << 3);
    gload_lds16(g, lb);
    gload_lds16(g + (size_t)64 * K, lb + 8192);
  };
  const int arow = (w >> 2) * 64 + ln15;
  const int brow = (w & 3) * 32 + ln15;
  const int rsw = ln15 & 7;
  auto LDA = [&](const char* cb, int qm, short8_t (&dst)[4][2]) {
    #pragma unroll
    for (int mf = 0; mf < 4; ++mf)
      #pragma unroll
      for (int kk = 0; kk < 2; ++kk)
        dst[mf][kk] = *(const short8_t*)(cb + qm * 16384 + (arow + mf * 16) * 128 +
                                         (((kk * 4 + lh) ^ rsw) << 4));
  };
  auto LDB = [&](const char* cb, int qn, short8_t (&dst)[2][2]) {
    #pragma unroll
    for (int nf = 0; nf < 2; ++nf)
      #pragma unroll
      for (int kk = 0; kk < 2; ++kk)
        dst[nf][kk] = *(const short8_t*)(cb + 32768 + qn * 16384 + (brow + nf * 16) * 128 +
                                         (((kk * 4 + lh) ^ rsw) << 4));
  };

  // ---- prologue: stage tiles 0 and 1 fully; retire tile 0 (tile 1 in flight) ----
  {
    char* b0 = smem;
    char* b1 = smem + 65536;
    stageA(b0, 0, 0); stageB(b0, 0, 0); stageA(b0, 1, 0); stageB(b0, 1, 0);
    stageA(b1, 0, 1); stageB(b1, 0, 1); stageA(b1, 1, 1); stageB(b1, 1, 1);
  }
  WAITVM(8);
  PBARRIER;

  for (int T = 0; T < NT; ++T) {
    char* cb = smem + (T & 1) * 65536;
    const bool s2 = (T + 2 < NT);
    // ---- ph1: Q00 (reads A0,B0 of T) ----
    LDA(cb, 0, af); LDB(cb, 0, bfB0);
    PBARRIER;
    MFMAQ(0, af, bfB0);
    PBARRIER;
    // ---- ph2: Q10 (reads A1); stage A0,B0(T+2) -> cb (readers done ph1) ----
    LDA(cb, 1, af2);
    if (s2) { stageA(cb, 0, T + 2); stageB(cb, 0, T + 2); }
    PBARRIER;
    MFMAQ(1, af2, bfB0);
    PBARRIER;
    // ---- ph3: Q11 (reads B1); stage A1(T+2) -> cb (readers done ph2) ----
    LDB(cb, 1, bfB1);
    if (s2) stageA(cb, 1, T + 2);
    PBARRIER;
    MFMAQ(2, af2, bfB1);
    PBARRIER;
    // ---- ph4: Q01 (no reads; af=A0, bfB1); stage B1(T+2) -> cb (readers done ph3) ----
    if (s2) stageB(cb, 1, T + 2);
    if (s2)               { WAITVM(8); }   // retire T+1's 8; keep T+2's 8 in flight
    else if (T + 1 < NT)  { WAITVM(0); }   // tail: drain tile NT-1's stages
    PBARRIER;
    MFMAQ(3, af, bfB1);
    PBARRIER;
  }

  // ---- epilogue ----
  const int rw = (w >> 2) * 64, cw = (w & 3) * 32;
  #pragma unroll
  for (int qi = 0; qi < 4; ++qi) {
    const int qm = (qi == 1 || qi == 2) ? 1 : 0;
    const int qn = (qi >= 2) ? 1 : 0;
    #pragma unroll
    for (int mf = 0; mf < 4; ++mf)
      #pragma unroll
      for (int nf = 0; nf < 2; ++nf)
        #pragma unroll
        for (int e = 0; e < 4; ++e) {
          int row = bm * 256 + qm * 128 + rw + mf * 16 + lh * 4 + e;
          int col = bn * 256 + qn * 128 + cw + nf * 16 + ln15;
          float v = acc[qi][mf][nf][e];
          if (MODE == 2) {
            float pv = __shfl_xor(v, 1);        // partner holds col^1 (same row)
            int d = col & 127, hh = col >> 7;
            int s = row & (Sc - 1), bb = row >> 10;
            float2 cs = *(const float2*)(tbl + (size_t)(s * 64 + (d >> 1)) * 2);
            float o = (d & 1) ? (v * cs.x + pv * cs.y) : (v * cs.x - pv * cs.y);
            o *= 0.08838834764831845f;
            ((u16*)Cv)[(((size_t)(bb * Hc + hh) * Sc + s) << 7) + d] = f2bf(o);
          } else {
            size_t idx = (size_t)row * N + col;
            ((float*)Cv)[idx] = v;
          }
        }
  }
}

// ---------------- Fused K+V projection GEMM (each-frag-once, counted vmcnt) ----------------
#define MFMAKV(QM, AF)                                                                   \
  do {                                                                                   \
    __builtin_amdgcn_s_setprio(1);                                                       \
    _Pragma("unroll") for (int mf = 0; mf < 4; ++mf)                                     \
      _Pragma("unroll") for (int nf = 0; nf < 2; ++nf)                                   \
        _Pragma("unroll") for (int kk = 0; kk < 2; ++kk)                                 \
          acc[QM][mf][nf] = __builtin_amdgcn_mfma_f32_16x16x32_bf16(                     \
              AF[mf][kk], bf[nf][kk], acc[QM][mf][nf], 0, 0, 0);                         \
    __builtin_amdgcn_s_setprio(0);                                                       \
  } while (0)

__global__ __launch_bounds__(512, 1) void gemm_kv(const u16* __restrict__ A, const u16* __restrict__ BT,
                                                  u16* __restrict__ Krp, u16* __restrict__ Vtp,
                                                  const float* __restrict__ tbl) {
  extern __shared__ char smem[];   // A dbuf 2x32KB @0 | B dbuf 2x16KB @65536 = 98304 B
  const int t = threadIdx.x, l = t & 63, w = t >> 6;
  const int ln15 = l & 15, lh = l >> 4;
  const int K = 4096, NT = 64;

  int id = blockIdx.x;
  int swz = (id & 7) * 32 + (id >> 3);      // 256 blocks, XCD-bijective
  const int bm = swz >> 4, bn = swz & 15;

  const u16* Ag = A + (size_t)bm * 256 * K;
  const u16* Bg = BT + (size_t)bn * 128 * K;

  f32x4 acc[2][4][2];
  #pragma unroll
  for (int q = 0; q < 2; ++q)
    #pragma unroll
    for (int mf = 0; mf < 4; ++mf)
      #pragma unroll
      for (int nf = 0; nf < 2; ++nf) acc[q][mf][nf] = f32x4{0.f, 0.f, 0.f, 0.f};
  short8_t af[4][2], af2[4][2], bf[2][2];

  const int srow = (l >> 3);
  const int sck  = (l & 7) ^ srow;
  auto stageA = [&](int buf, int h, int tt) {   // one A half = 128 rows x 64 K = 16KB
    char* lb = smem + buf * 32768 + h * 16384 + w * 2048;
    const u16* g = Ag + (size_t)(h * 128 + w * 16 + srow) * K + tt * 64 + (sck << 3);
    gload_lds16(g, lb);
    gload_lds16(g + (size_t)8 * K, lb + 1024);
  };
  auto stageB = [&](int buf, int tt) {          // B tile = 128 rows x 64 K = 16KB
    char* lb = smem + 65536 + buf * 16384 + w * 2048;
    const u16* g = Bg + (size_t)(w * 16 + srow) * K + tt * 64 + (sck << 3);
    gload_lds16(g, lb);
    gload_lds16(g + (size_t)8 * K, lb + 1024);
  };
  const int arow = (w >> 2) * 64 + ln15;        // within A half
  const int brow = (w & 3) * 32 + ln15;         // within B tile (128 rows)
  const int rsw = ln15 & 7;
  auto LDA = [&](int buf, int qm, short8_t (&dst)[4][2]) {
    #pragma unroll
    for (int mf = 0; mf < 4; ++mf)
      #pragma unroll
      for (int kk = 0; kk < 2; ++kk)
        dst[mf][kk] = *(const short8_t*)(smem + buf * 32768 + qm * 16384 + (arow + mf * 16) * 128 +
                                         (((kk * 4 + lh) ^ rsw) << 4));
  };
  auto LDB = [&](int buf) {
    #pragma unroll
    for (int nf = 0; nf < 2; ++nf)
      #pragma unroll
      for (int kk = 0; kk < 2; ++kk)
        bf[nf][kk] = *(const short8_t*)(smem + 65536 + buf * 16384 + (brow + nf * 16) * 128 +
                                        (((kk * 4 + lh) ^ rsw) << 4));
  };

  // prologue: stage tile 0 (A0,B,A1); retire all but A1
  stageA(0, 0, 0);
  stageB(0, 0);
  stageA(0, 1, 0);
  WAITVM(2);
  PBARRIER;

  for (int T = 0; T < NT; ++T) {
    const int cb = T & 1, nb = cb ^ 1;
    const bool st = (T + 1 < NT);
    LDB(cb);
    if (st) { stageA(nb, 0, T + 1); stageB(nb, T + 1); stageA(nb, 1, T + 1); }
    // p1: A0 phase
    LDA(cb, 0, af);
    MFMAKV(0, af);
    // p2: A1 phase
    if (st) { WAITVM(6); } else { WAITVM(0); }   // retire A1(T)
    LDA(cb, 1, af2);
    MFMAKV(1, af2);
    if (st) { WAITVM(2); }                       // retire A0,B of T+1
    PBARRIER;
  }

  // epilogue
  #pragma unroll
  for (int qm = 0; qm < 2; ++qm)
    #pragma unroll
    for (int mf = 0; mf < 4; ++mf)
      #pragma unroll
      for (int nf = 0; nf < 2; ++nf)
        #pragma unroll
        for (int e = 0; e < 4; ++e) {
          int row = bm * 256 + qm * 128 + (w >> 2) * 64 + mf * 16 + lh * 4 + e;
          int col = bn * 128 + (w & 3) * 32 + nf * 16 + ln15;
          float v = acc[qm][mf][nf][e];
          float pv = __shfl_xor(v, 1);
          int s = row & (Sc - 1), bb = row >> 10;
          if (col < 1024) {          // K + RoPE
            int hkv = col >> 7, d = col & 127;
            float2 cs = *(const float2*)(tbl + (size_t)(s * 64 + (d >> 1)) * 2);
            float o = (d & 1) ? (v * cs.x + pv * cs.y) : (v * cs.x - pv * cs.y);
            Krp[(((size_t)(bb * HKVc + hkv) * Sc + s) << 7) + d] = f2bf(o);
          } else {                   // V, sigma-permuted transpose
            int vc = col - 1024;
            int hkv = vc >> 7, d = vc & 127;
            int sl = s & 63;
            int sg = (sl & 32) | (((sl >> 2) & 3) << 3) | (((sl >> 4) & 1) << 2) | (sl & 3);
            Vtp[((size_t)(bb * HKVc + hkv) * Dc + d) * Sc + (s & ~63) + sg] = f2bf(v);
          }
        }
}

// ---------------- Flash attention (causal, GQA), swapped-QK^T, P in registers ----------------
__global__ __launch_bounds__(512, 4) void attn_k(const u16* __restrict__ Q, const u16* __restrict__ Kr,
                                                 const u16* __restrict__ Vt, u16* __restrict__ AO) {
  extern __shared__ char smem[];
  const int t = threadIdx.x, l = t & 63, w = t >> 6;
  const int qb = (int)gridDim.x - 1 - (int)blockIdx.x;   // big causal tiles dispatched first
  const int h = blockIdx.y, b = blockIdx.z;
  const int hkv = h >> 2;
  const int ln15 = l & 15, lh = l >> 4;
  const int NT = 2 * qb + 2;

  const u16* Kg0 = Kr + (size_t)(b * HKVc + hkv) * Sc * Dc;
  const u16* Vg0 = Vt + (size_t)(b * HKVc + hkv) * Dc * Sc;

  auto stageK = [&](int buf, int tt) {
    char* base = smem + buf * 16384 + w * 2048;
    #pragma unroll
    for (int i = 0; i < 2; ++i) {
      int row = w * 8 + i * 4 + (l >> 4);
      int c = l & 15;
      gload_lds16(Kg0 + (size_t)(tt * 64 + row) * Dc + ((c ^ (row & 7)) << 3), base + i * 1024);
    }
  };
  auto stageV = [&](int buf, int tt) {
    char* base = smem + 32768 + buf * 16384 + w * 2048;
    #pragma unroll
    for (int i = 0; i < 2; ++i) {
      int d = w * 16 + i * 8 + (l >> 3);
      int c = l & 7;
      gload_lds16(Vg0 + (size_t)d * Sc + tt * 64 + ((c ^ (d & 7)) << 3), base + i * 1024);
    }
  };

  short8_t qf[4];
  {
    int q = qb * 128 + w * 16 + ln15;
    const u16* qp = Q + ((size_t)(b * Hc + h) * Sc + q) * Dc + lh * 8;
    #pragma unroll
    for (int ks = 0; ks < 4; ++ks) qf[ks] = *(const short8_t*)(qp + ks * 32);
  }
  SBAR;   // qf loads issued before staging (vmcnt ordering)

  f32x4 oacc[8];
  #pragma unroll
  for (int i = 0; i < 8; ++i) oacc[i] = f32x4{0.f, 0.f, 0.f, 0.f};
  float mrun = -1e30f, lrun = 0.f;

  stageK(0, 0); stageV(0, 0);
  stageK(1, 1); stageV(1, 1);

  const int qmaxw = qb * 128 + w * 16 + 15;
  const int qlane = qb * 128 + w * 16 + ln15;

  for (int T = 0; T < NT; ++T) {
    if (T < NT - 1) { WAITVM(4); } else { WAITVM(0); }
    PBARRIER;
    const char* Kb = smem + (T & 1) * 16384;
    const char* Vb = smem + 32768 + (T & 1) * 16384;

    if (T * 64 <= qmaxw) {
      f32x4 sf[4];
      #pragma unroll
      for (int fc = 0; fc < 4; ++fc) {
        sf[fc] = f32x4{0.f, 0.f, 0.f, 0.f};
        int kvr = fc * 16 + ln15;
        #pragma unroll
        for (int ks = 0; ks < 4; ++ks) {
          int chunk = ks * 4 + lh;
          short8_t kf = *(const short8_t*)(Kb + kvr * 256 + ((chunk ^ (kvr & 7)) << 4));
          sf[fc] = __builtin_amdgcn_mfma_f32_16x16x32_bf16(kf, qf[ks], sf[fc], 0, 0, 0);
        }
      }
      if (T * 64 + 63 > qb * 128 + w * 16) {
        #pragma unroll
        for (int fc = 0; fc < 4; ++fc)
          #pragma unroll
          for (int j = 0; j < 4; ++j) {
            int kvg = T * 64 + fc * 16 + lh * 4 + j;
            if (kvg > qlane) sf[fc][j] = -1e30f;
          }
      }
      float mx = sf[0][0];
      #pragma unroll
      for (int fc = 0; fc < 4; ++fc)
        #pragma unroll
        for (int j = 0; j < 4; ++j) mx = fmaxf(mx, sf[fc][j]);
      mx = fmaxf(mx, __shfl_xor(mx, 16));
      mx = fmaxf(mx, __shfl_xor(mx, 32));
      float mnew = fmaxf(mrun, mx);
      float alpha = __expf(mrun - mnew);
      mrun = mnew;
      float rs = 0.f;
      #pragma unroll
      for (int fc = 0; fc < 4; ++fc)
        #pragma unroll
        for (int j = 0; j < 4; ++j) {
          float p = __expf(sf[fc][j] - mnew);
          sf[fc][j] = p;
          rs += p;
        }
      rs += __shfl_xor(rs, 16);
      rs += __shfl_xor(rs, 32);
      lrun = lrun * alpha + rs;
      float arow[4];
      #pragma unroll
      for (int j = 0; j < 4; ++j) arow[j] = __shfl(alpha, (l & 48) | (lh * 4 + j));
      #pragma unroll
      for (int fd = 0; fd < 8; ++fd)
        #pragma unroll
        for (int j = 0; j < 4; ++j) oacc[fd][j] *= arow[j];
      short8_t pa[2];
      #pragma unroll
      for (int ks = 0; ks < 2; ++ks)
        #pragma unroll
        for (int b2 = 0; b2 < 2; ++b2)
          #pragma unroll
          for (int j = 0; j < 4; ++j) pa[ks][b2 * 4 + j] = (short)f2bf(sf[ks * 2 + b2][j]);
      #pragma unroll
      for (int fd = 0; fd < 8; ++fd) {
        int dcol = fd * 16 + ln15;
        #pragma unroll
        for (int ks = 0; ks < 2; ++ks) {
          int chunk = ks * 4 + lh;
          short8_t vf = *(const short8_t*)(Vb + dcol * 128 + ((chunk ^ (dcol & 7)) << 4));
          oacc[fd] = __builtin_amdgcn_mfma_f32_16x16x32_bf16(pa[ks], vf, oacc[fd], 0, 0, 0);
        }
      }
    }
    PBARRIER;
    if (T + 2 < NT) { stageK(T & 1, T + 2); stageV(T & 1, T + 2); }
  }

  float linv[4];
  #pragma unroll
  for (int j = 0; j < 4; ++j) linv[j] = 1.f / __shfl(lrun, (l & 48) | (lh * 4 + j));
  #pragma unroll
  for (int j = 0; j < 4; ++j) {
    int q = qb * 128 + w * 16 + lh * 4 + j;
    u16* op = AO + (size_t)(b * Sc + q) * DIMc + h * Dc + ln15;
    #pragma unroll
    for (int fd = 0; fd < 8; ++fd) op[fd * 16] = f2bf(oacc[fd][j] * linv[j]);
  }
}

extern "C" void kernel_launch(void* const* d_in, const int* in_sizes, int n_in,
                              void* d_out, int out_size, void* d_ws, size_t ws_size,
                              hipStream_t stream) {
  const float* x  = (const float*)d_in[0];
  const float* wq = (const float*)d_in[1];
  const float* wk = (const float*)d_in[2];
  const float* wv = (const float*)d_in[3];
  const float* wo = (const float*)d_in[4];
  float* out = (float*)d_out;

  char* ws = (char*)d_ws;
  size_t off = 0;
  auto alloc = [&](size_t bytes) -> char* {
    char* p = ws + off;
    off += (bytes + 255) & ~(size_t)255;
    return p;
  };
  float* tbl  = (float*)alloc((size_t)Sc * 64 * 2 * 4);
  u16* xb    = (u16*)alloc((size_t)BS * DIMc * 2);     // x bf16; later reused as AO
  u16* wqT   = (u16*)alloc((size_t)4096 * 4096 * 2);   // wqT; later woT
  u16* wkvT  = (u16*)alloc((size_t)2048 * 4096 * 2);   // [wkT ; wvT]
  u16* Qb    = (u16*)alloc((size_t)BS * 4096 * 2);     // roped Q in [b][h][s][d]
  u16* Krp   = (u16*)alloc((size_t)BS * 1024 * 2);     // roped K in [b][hkv][s][d]
  u16* Vtp   = (u16*)alloc((size_t)BS * 1024 * 2);     // V in [b][hkv][d][sigma(s)]
  u16* AO = xb;    // alias: xb dead after K/V GEMM
  u16* woT = wqT;  // alias: wqT dead after Q GEMM

  rope_table_k<<<(Sc * 64) / 256, 256, 0, stream>>>(tbl);
  f32_to_bf16_k<<<(BS * DIMc / 4) / 256, 256, 0, stream>>>(x, xb, BS * DIMc / 4);

  transpose_w_k<<<dim3(64, 64), 256, 0, stream>>>(wq, wqT, 4096, 4096);
  gemm256<2><<<256, 512, 131072, stream>>>(xb, wqT, Qb, tbl, 4096, 4096, 4096);  // Q + RoPE + relayout

  transpose_w_k<<<dim3(16, 64), 256, 0, stream>>>(wk, wkvT, 4096, 1024);
  transpose_w_k<<<dim3(16, 64), 256, 0, stream>>>(wv, wkvT + (size_t)1024 * 4096, 4096, 1024);
  gemm_kv<<<256, 512, 98304, stream>>>(xb, wkvT, Krp, Vtp, tbl);                 // K+RoPE, V+sigma-transpose

  attn_k<<<dim3(8, Hc, Bc), 512, 65536, stream>>>(Qb, Krp, Vtp, AO);

  transpose_w_k<<<dim3(64, 64), 256, 0, stream>>>(wo, woT, 4096, 4096);
  gemm256<1><<<256, 512, 131072, stream>>>(AO, woT, out, tbl, 4096, 4096, 4096);
}

// Round 13
// 470.769 us; speedup vs baseline: 1.0211x; 1.0211x over previous
//
#include <hip/hip_runtime.h>

typedef unsigned short u16;
typedef unsigned int u32;
typedef __attribute__((ext_vector_type(8))) short short8_t;  // 8 bf16 (4 VGPRs)
typedef __attribute__((ext_vector_type(4))) float f32x4;

static constexpr int Bc = 4, Sc = 1024, Hc = 32, HKVc = 8, Dc = 128;
static constexpr int BS = Bc * Sc;     // 4096 rows
static constexpr int DIMc = 4096;

__device__ __forceinline__ u16 f2bf(float f) {
  u32 u = __float_as_uint(f);
  u32 r = (u + 0x7fffu + ((u >> 16) & 1u)) >> 16;  // RNE
  return (u16)r;
}
__device__ __forceinline__ float bf2f(u16 u) {
  return __uint_as_float(((u32)u) << 16);
}
__device__ __forceinline__ void gload_lds16(const void* g, void* l) {
  __builtin_amdgcn_global_load_lds((const __attribute__((address_space(1))) void*)g,
                                   (__attribute__((address_space(3))) void*)l, 16, 0, 0);
}

#define SBAR __builtin_amdgcn_sched_barrier(0)
#define PBARRIER do { SBAR; __builtin_amdgcn_s_barrier(); SBAR; } while (0)
#define WAITVM(N) asm volatile("s_waitcnt vmcnt(" #N ")" ::: "memory")

// ---------------- RoPE table: cos/sin for (s, i) ----------------
__global__ void rope_table_k(float* __restrict__ tbl) {
  int i = blockIdx.x * 256 + threadIdx.x;     // 1024*64
  int s = i >> 6, fi = i & 63;
  float freq = powf(10000.f, -(float)fi / 64.f);
  float ang = (float)s * freq;
  float sv, cv;
  sincosf(ang, &sv, &cv);
  tbl[2 * i] = cv;
  tbl[2 * i + 1] = sv;
}

// ---------------- fp32 -> bf16 convert (vectorized) ----------------
__global__ void f32_to_bf16_k(const float* __restrict__ in, u16* __restrict__ out, int n4) {
  int i = blockIdx.x * 256 + threadIdx.x;
  if (i >= n4) return;
  float4 v = *(const float4*)(in + (size_t)i * 4);
  uint2 pk;
  pk.x = (u32)f2bf(v.x) | ((u32)f2bf(v.y) << 16);
  pk.y = (u32)f2bf(v.z) | ((u32)f2bf(v.w) << 16);
  *(uint2*)(out + (size_t)i * 4) = pk;
}

// ---------------- W (K,N) fp32 -> WT (N,K) bf16, tiled transpose ----------------
__global__ __launch_bounds__(256) void transpose_w_k(const float* __restrict__ W, u16* __restrict__ WT,
                                                     int Kdim, int Ndim) {
  __shared__ float tile[64 * 65];
  const int t = threadIdx.x;
  const int n0 = blockIdx.x * 64, k0 = blockIdx.y * 64;
  #pragma unroll
  for (int p = 0; p < 4; ++p) {
    int idx = p * 256 + t;           // 1024 float4 chunks
    int r = idx >> 4, c = (idx & 15) * 4;
    float4 v = *(const float4*)(W + (size_t)(k0 + r) * Ndim + n0 + c);
    tile[r * 65 + c + 0] = v.x;
    tile[r * 65 + c + 1] = v.y;
    tile[r * 65 + c + 2] = v.z;
    tile[r * 65 + c + 3] = v.w;
  }
  __syncthreads();
  #pragma unroll
  for (int p = 0; p < 2; ++p) {
    int idx = p * 256 + t;           // 512 chunks of 8 bf16
    int n = idx >> 3, c = (idx & 7) * 8;
    alignas(16) u16 o[8];
    #pragma unroll
    for (int i = 0; i < 8; ++i) o[i] = f2bf(tile[(c + i) * 65 + n]);
    *(uint4*)(WT + (size_t)(n0 + n) * Kdim + k0 + c) = *(const uint4*)o;
  }
}

// ---------------- 256^2-tile GEMM, each-frag-once / counted-vmcnt (R11 best) ----------------
// MODE 1: f32 C row-major; MODE 2: bf16 + fused RoPE + relayout to Q[b][h][s][d].
#define MFMAQ(QI, AF, BF)                                                                \
  do {                                                                                   \
    __builtin_amdgcn_s_setprio(1);                                                       \
    _Pragma("unroll") for (int mf = 0; mf < 4; ++mf)                                     \
      _Pragma("unroll") for (int nf = 0; nf < 2; ++nf)                                   \
        _Pragma("unroll") for (int kk = 0; kk < 2; ++kk)                                 \
          acc[QI][mf][nf] = __builtin_amdgcn_mfma_f32_16x16x32_bf16(                     \
              AF[mf][kk], BF[nf][kk], acc[QI][mf][nf], 0, 0, 0);                         \
    __builtin_amdgcn_s_setprio(0);                                                       \
  } while (0)

template <int MODE>
__global__ __launch_bounds__(512, 2) void gemm256(const u16* __restrict__ A, const u16* __restrict__ BT,
                                                  void* __restrict__ Cv, const float* __restrict__ tbl,
                                                  int M, int N, int K) {
  extern __shared__ char smem[];   // 131072 B
  const int t = threadIdx.x, l = t & 63, w = t >> 6;
  const int ln15 = l & 15, lh = l >> 4;
  const int NT = K >> 6;

  int id = blockIdx.x;
  int nwg = gridDim.x;
  int swz = ((nwg & 7) == 0) ? ((id & 7) * (nwg >> 3) + (id >> 3)) : id;
  const int nbn = N >> 8;
  const int bm = swz / nbn, bn = swz % nbn;

  const u16* Ag = A + (size_t)bm * 256 * K;
  const u16* Bg = BT + (size_t)bn * 256 * K;

  f32x4 acc[4][4][2];
  #pragma unroll
  for (int q = 0; q < 4; ++q)
    #pragma unroll
    for (int mf = 0; mf < 4; ++mf)
      #pragma unroll
      for (int nf = 0; nf < 2; ++nf) acc[q][mf][nf] = f32x4{0.f, 0.f, 0.f, 0.f};
  short8_t af[4][2], af2[4][2], bfB0[2][2], bfB1[2][2];

  const int srow = (l >> 3);
  const int sck  = (l & 7) ^ srow;
  auto stageA = [&](char* bufbase, int h, int tt) {
    char* lb = bufbase + h * 16384 + w * 1024;
    const u16* g = Ag + (size_t)(h * 128 + w * 8 + srow) * K + tt * 64 + (sck << 3);
    gload_lds16(g, lb);
    gload_lds16(g + (size_t)64 * K, lb + 8192);
  };
  auto stageB = [&](char* bufbase, int h, int tt) {
    char* lb = bufbase + 32768 + h * 16384 + w * 1024;
    const u16* g = Bg + (size_t)(h * 128 + w * 8 + srow) * K + tt * 64 + (sck << 3);
    gload_lds16(g, lb);
    gload_lds16(g + (size_t)64 * K, lb + 8192);
  };
  const int arow = (w >> 2) * 64 + ln15;
  const int brow = (w & 3) * 32 + ln15;
  const int rsw = ln15 & 7;
  auto LDA = [&](const char* cb, int qm, short8_t (&dst)[4][2]) {
    #pragma unroll
    for (int mf = 0; mf < 4; ++mf)
      #pragma unroll
      for (int kk = 0; kk < 2; ++kk)
        dst[mf][kk] = *(const short8_t*)(cb + qm * 16384 + (arow + mf * 16) * 128 +
                                         (((kk * 4 + lh) ^ rsw) << 4));
  };
  auto LDB = [&](const char* cb, int qn, short8_t (&dst)[2][2]) {
    #pragma unroll
    for (int nf = 0; nf < 2; ++nf)
      #pragma unroll
      for (int kk = 0; kk < 2; ++kk)
        dst[nf][kk] = *(const short8_t*)(cb + 32768 + qn * 16384 + (brow + nf * 16) * 128 +
                                         (((kk * 4 + lh) ^ rsw) << 4));
  };

  // ---- prologue: stage tile 0 (A0,B0,B1,A1); retire all but A1 ----
  stageA(smem, 0, 0);
  stageB(smem, 0, 0);
  stageB(smem, 1, 0);
  stageA(smem, 1, 0);
  WAITVM(2);
  PBARRIER;

  for (int T = 0; T < NT; ++T) {
    char* cb = smem + (T & 1) * 65536;
    char* nb = smem + ((T & 1) ^ 1) * 65536;
    const bool s1 = (T + 1 < NT);
    // resident B for this tile (cb valid post-barrier except A1, handled below)
    LDB(cb, 0, bfB0);
    LDB(cb, 1, bfB1);
    // stage ALL of T+1 now (order A0,B0,B1,A1) -> full-tile latency lead
    if (s1) {
      stageA(nb, 0, T + 1);
      stageB(nb, 0, T + 1);
      stageB(nb, 1, T + 1);
      stageA(nb, 1, T + 1);
    }
    // p1: A0 phase
    LDA(cb, 0, af);
    MFMAQ(0, af, bfB0);     // Q00
    MFMAQ(3, af, bfB1);     // Q01
    // p2: A1 phase (A1(T) retired: it was issued one tile ago)
    if (s1) { WAITVM(8); } else { WAITVM(0); }
    LDA(cb, 1, af2);
    MFMAQ(1, af2, bfB0);    // Q10
    MFMAQ(2, af2, bfB1);    // Q11
    if (s1) { WAITVM(2); }  // retire A0,B0,B1 of T+1; keep A1(T+1) in flight
    PBARRIER;               // all waves done reading cb; nb (minus A1) valid
  }

  // ---- epilogue ----
  const int rw = (w >> 2) * 64, cw = (w & 3) * 32;
  #pragma unroll
  for (int qi = 0; qi < 4; ++qi) {
    const int qm = (qi == 1 || qi == 2) ? 1 : 0;
    const int qn = (qi >= 2) ? 1 : 0;
    #pragma unroll
    for (int mf = 0; mf < 4; ++mf)
      #pragma unroll
      for (int nf = 0; nf < 2; ++nf)
        #pragma unroll
        for (int e = 0; e < 4; ++e) {
          int row = bm * 256 + qm * 128 + rw + mf * 16 + lh * 4 + e;
          int col = bn * 256 + qn * 128 + cw + nf * 16 + ln15;
          float v = acc[qi][mf][nf][e];
          if (MODE == 2) {
            float pv = __shfl_xor(v, 1);        // partner holds col^1 (same row)
            int d = col & 127, hh = col >> 7;
            int s = row & (Sc - 1), bb = row >> 10;
            float2 cs = *(const float2*)(tbl + (size_t)(s * 64 + (d >> 1)) * 2);
            float o = (d & 1) ? (v * cs.x + pv * cs.y) : (v * cs.x - pv * cs.y);
            o *= 0.08838834764831845f;
            ((u16*)Cv)[(((size_t)(bb * Hc + hh) * Sc + s) << 7) + d] = f2bf(o);
          } else {
            size_t idx = (size_t)row * N + col;
            ((float*)Cv)[idx] = v;
          }
        }
  }
}

// ---------------- Fused K+V projection GEMM, BM=128 x BN=256 ----------------
// C[4096, 2048] = xb @ [wkT ; wvT]^T. Grid 32x8 = 256 blocks, per-wave 64x64
// output (A 8 + B 8 reads per 32 MFMA). R11-style A-resident / counted-vmcnt /
// 1-barrier loop. Epilogue: cols<1024 -> K+RoPE into Krp[b][hkv][s][d];
// cols>=1024 -> V into Vtp[b][hkv][d][sigma(s)].
#define MFMAKV(PH, BF)                                                                   \
  do {                                                                                   \
    __builtin_amdgcn_s_setprio(1);                                                       \
    _Pragma("unroll") for (int mf = 0; mf < 4; ++mf)                                     \
      _Pragma("unroll") for (int nf = 0; nf < 2; ++nf)                                   \
        _Pragma("unroll") for (int kk = 0; kk < 2; ++kk)                                 \
          acc[mf][(PH) * 2 + nf] = __builtin_amdgcn_mfma_f32_16x16x32_bf16(              \
              af[mf][kk], BF[nf][kk], acc[mf][(PH) * 2 + nf], 0, 0, 0);                  \
    __builtin_amdgcn_s_setprio(0);                                                       \
  } while (0)

__global__ __launch_bounds__(512, 1) void gemm_kv(const u16* __restrict__ A, const u16* __restrict__ BT,
                                                  u16* __restrict__ Krp, u16* __restrict__ Vtp,
                                                  const float* __restrict__ tbl) {
  extern __shared__ char smem[];   // A dbuf 2x16KB @0 | B dbuf 2x32KB @32768 = 98304 B
  const int t = threadIdx.x, l = t & 63, w = t >> 6;
  const int ln15 = l & 15, lh = l >> 4;
  const int K = 4096, NT = 64;

  int id = blockIdx.x;
  int swz = (id & 7) * 32 + (id >> 3);      // 256 blocks, XCD-bijective
  const int bm = swz >> 3, bn = swz & 7;    // 32 x 8

  const u16* Ag = A + (size_t)bm * 128 * K;
  const u16* Bg = BT + (size_t)bn * 256 * K;

  f32x4 acc[4][4];
  #pragma unroll
  for (int mf = 0; mf < 4; ++mf)
    #pragma unroll
    for (int nf = 0; nf < 4; ++nf) acc[mf][nf] = f32x4{0.f, 0.f, 0.f, 0.f};
  short8_t af[4][2], bfL[2][2], bfR[2][2];

  const int srow = (l >> 3);
  const int sck  = (l & 7) ^ srow;
  auto stageA = [&](int buf, int tt) {          // A tile = 128 rows x 64 K = 16KB
    char* lb = smem + buf * 16384 + w * 1024;
    const u16* g = Ag + (size_t)(w * 8 + srow) * K + tt * 64 + (sck << 3);
    gload_lds16(g, lb);
    gload_lds16(g + (size_t)64 * K, lb + 8192);
  };
  auto stageB = [&](int buf, int h, int tt) {   // one B half = 128 rows x 64 K = 16KB
    char* lb = smem + 32768 + buf * 32768 + h * 16384 + w * 1024;
    const u16* g = Bg + (size_t)(h * 128 + w * 8 + srow) * K + tt * 64 + (sck << 3);
    gload_lds16(g, lb);
    gload_lds16(g + (size_t)64 * K, lb + 8192);
  };
  const int arow = (w >> 2) * 64 + ln15;        // 0..127 within A tile
  const int bcol0 = (w & 3) * 64;               // wave's B col group (4 nf x 16)
  const int rsw = ln15 & 7;
  auto LDA = [&](int buf) {
    #pragma unroll
    for (int mf = 0; mf < 4; ++mf)
      #pragma unroll
      for (int kk = 0; kk < 2; ++kk)
        af[mf][kk] = *(const short8_t*)(smem + buf * 16384 + (arow + mf * 16) * 128 +
                                        (((kk * 4 + lh) ^ rsw) << 4));
  };
  auto LDB = [&](int buf, int half, short8_t (&dst)[2][2]) {
    #pragma unroll
    for (int nf = 0; nf < 2; ++nf)
      #pragma unroll
      for (int kk = 0; kk < 2; ++kk) {
        int brow = bcol0 + (half * 2 + nf) * 16 + ln15;   // 0..255
        dst[nf][kk] = *(const short8_t*)(smem + 32768 + buf * 32768 + brow * 128 +
                                         (((kk * 4 + lh) ^ rsw) << 4));
      }
  };

  // prologue: stage tile 0 (A, B0, B1); retire A,B0 (B1 stays in flight)
  stageA(0, 0);
  stageB(0, 0, 0);
  stageB(0, 1, 0);
  WAITVM(2);
  PBARRIER;

  for (int T = 0; T < NT; ++T) {
    const int cb = T & 1, nb = cb ^ 1;
    const bool st = (T + 1 < NT);
    LDA(cb);                 // A resident for the tile
    LDB(cb, 0, bfL);
    if (st) { stageA(nb, T + 1); stageB(nb, 0, T + 1); stageB(nb, 1, T + 1); }
    // p1: left B half
    MFMAKV(0, bfL);
    if (st) { WAITVM(6); } else { WAITVM(0); }   // retire B1(T)
    LDB(cb, 1, bfR);
    // p2: right B half
    MFMAKV(1, bfR);
    if (st) { WAITVM(2); }                       // retire A,B0(T+1); keep B1(T+1)
    PBARRIER;
  }

  // epilogue
  #pragma unroll
  for (int mf = 0; mf < 4; ++mf)
    #pragma unroll
    for (int nf = 0; nf < 4; ++nf)
      #pragma unroll
      for (int e = 0; e < 4; ++e) {
        int row = bm * 128 + (w >> 2) * 64 + mf * 16 + lh * 4 + e;
        int col = bn * 256 + bcol0 + nf * 16 + ln15;
        float v = acc[mf][nf][e];
        float pv = __shfl_xor(v, 1);
        int s = row & (Sc - 1), bb = row >> 10;
        if (col < 1024) {          // K + RoPE
          int hkv = col >> 7, d = col & 127;
          float2 cs = *(const float2*)(tbl + (size_t)(s * 64 + (d >> 1)) * 2);
          float o = (d & 1) ? (v * cs.x + pv * cs.y) : (v * cs.x - pv * cs.y);
          Krp[(((size_t)(bb * HKVc + hkv) * Sc + s) << 7) + d] = f2bf(o);
        } else {                   // V, sigma-permuted transpose
          int vc = col - 1024;
          int hkv = vc >> 7, d = vc & 127;
          int sl = s & 63;
          int sg = (sl & 32) | (((sl >> 2) & 3) << 3) | (((sl >> 4) & 1) << 2) | (sl & 3);
          Vtp[((size_t)(bb * HKVc + hkv) * Dc + d) * Sc + (s & ~63) + sg] = f2bf(v);
        }
      }
}

// ---------------- Flash attention (causal, GQA), swapped-QK^T, P in registers ----------------
__global__ __launch_bounds__(512, 4) void attn_k(const u16* __restrict__ Q, const u16* __restrict__ Kr,
                                                 const u16* __restrict__ Vt, u16* __restrict__ AO) {
  extern __shared__ char smem[];
  const int t = threadIdx.x, l = t & 63, w = t >> 6;
  const int qb = (int)gridDim.x - 1 - (int)blockIdx.x;   // big causal tiles dispatched first
  const int h = blockIdx.y, b = blockIdx.z;
  const int hkv = h >> 2;
  const int ln15 = l & 15, lh = l >> 4;
  const int NT = 2 * qb + 2;

  const u16* Kg0 = Kr + (size_t)(b * HKVc + hkv) * Sc * Dc;
  const u16* Vg0 = Vt + (size_t)(b * HKVc + hkv) * Dc * Sc;

  auto stageK = [&](int buf, int tt) {
    char* base = smem + buf * 16384 + w * 2048;
    #pragma unroll
    for (int i = 0; i < 2; ++i) {
      int row = w * 8 + i * 4 + (l >> 4);
      int c = l & 15;
      gload_lds16(Kg0 + (size_t)(tt * 64 + row) * Dc + ((c ^ (row & 7)) << 3), base + i * 1024);
    }
  };
  auto stageV = [&](int buf, int tt) {
    char* base = smem + 32768 + buf * 16384 + w * 2048;
    #pragma unroll
    for (int i = 0; i < 2; ++i) {
      int d = w * 16 + i * 8 + (l >> 3);
      int c = l & 7;
      gload_lds16(Vg0 + (size_t)d * Sc + tt * 64 + ((c ^ (d & 7)) << 3), base + i * 1024);
    }
  };

  short8_t qf[4];
  {
    int q = qb * 128 + w * 16 + ln15;
    const u16* qp = Q + ((size_t)(b * Hc + h) * Sc + q) * Dc + lh * 8;
    #pragma unroll
    for (int ks = 0; ks < 4; ++ks) qf[ks] = *(const short8_t*)(qp + ks * 32);
  }
  SBAR;   // qf loads issued before staging (vmcnt ordering)

  f32x4 oacc[8];
  #pragma unroll
  for (int i = 0; i < 8; ++i) oacc[i] = f32x4{0.f, 0.f, 0.f, 0.f};
  float mrun = -1e30f, lrun = 0.f;

  stageK(0, 0); stageV(0, 0);
  stageK(1, 1); stageV(1, 1);

  const int qmaxw = qb * 128 + w * 16 + 15;
  const int qlane = qb * 128 + w * 16 + ln15;

  for (int T = 0; T < NT; ++T) {
    if (T < NT - 1) { WAITVM(4); } else { WAITVM(0); }
    PBARRIER;
    const char* Kb = smem + (T & 1) * 16384;
    const char* Vb = smem + 32768 + (T & 1) * 16384;

    if (T * 64 <= qmaxw) {
      f32x4 sf[4];
      #pragma unroll
      for (int fc = 0; fc < 4; ++fc) {
        sf[fc] = f32x4{0.f, 0.f, 0.f, 0.f};
        int kvr = fc * 16 + ln15;
        #pragma unroll
        for (int ks = 0; ks < 4; ++ks) {
          int chunk = ks * 4 + lh;
          short8_t kf = *(const short8_t*)(Kb + kvr * 256 + ((chunk ^ (kvr & 7)) << 4));
          sf[fc] = __builtin_amdgcn_mfma_f32_16x16x32_bf16(kf, qf[ks], sf[fc], 0, 0, 0);
        }
      }
      if (T * 64 + 63 > qb * 128 + w * 16) {
        #pragma unroll
        for (int fc = 0; fc < 4; ++fc)
          #pragma unroll
          for (int j = 0; j < 4; ++j) {
            int kvg = T * 64 + fc * 16 + lh * 4 + j;
            if (kvg > qlane) sf[fc][j] = -1e30f;
          }
      }
      float mx = sf[0][0];
      #pragma unroll
      for (int fc = 0; fc < 4; ++fc)
        #pragma unroll
        for (int j = 0; j < 4; ++j) mx = fmaxf(mx, sf[fc][j]);
      mx = fmaxf(mx, __shfl_xor(mx, 16));
      mx = fmaxf(mx, __shfl_xor(mx, 32));
      float mnew = fmaxf(mrun, mx);
      float alpha = __expf(mrun - mnew);
      mrun = mnew;
      float rs = 0.f;
      #pragma unroll
      for (int fc = 0; fc < 4; ++fc)
        #pragma unroll
        for (int j = 0; j < 4; ++j) {
          float p = __expf(sf[fc][j] - mnew);
          sf[fc][j] = p;
          rs += p;
        }
      rs += __shfl_xor(rs, 16);
      rs += __shfl_xor(rs, 32);
      lrun = lrun * alpha + rs;
      float arow[4];
      #pragma unroll
      for (int j = 0; j < 4; ++j) arow[j] = __shfl(alpha, (l & 48) | (lh * 4 + j));
      #pragma unroll
      for (int fd = 0; fd < 8; ++fd)
        #pragma unroll
        for (int j = 0; j < 4; ++j) oacc[fd][j] *= arow[j];
      short8_t pa[2];
      #pragma unroll
      for (int ks = 0; ks < 2; ++ks)
        #pragma unroll
        for (int b2 = 0; b2 < 2; ++b2)
          #pragma unroll
          for (int j = 0; j < 4; ++j) pa[ks][b2 * 4 + j] = (short)f2bf(sf[ks * 2 + b2][j]);
      #pragma unroll
      for (int fd = 0; fd < 8; ++fd) {
        int dcol = fd * 16 + ln15;
        #pragma unroll
        for (int ks = 0; ks < 2; ++ks) {
          int chunk = ks * 4 + lh;
          short8_t vf = *(const short8_t*)(Vb + dcol * 128 + ((chunk ^ (dcol & 7)) << 4));
          oacc[fd] = __builtin_amdgcn_mfma_f32_16x16x32_bf16(pa[ks], vf, oacc[fd], 0, 0, 0);
        }
      }
    }
    PBARRIER;
    if (T + 2 < NT) { stageK(T & 1, T + 2); stageV(T & 1, T + 2); }
  }

  float linv[4];
  #pragma unroll
  for (int j = 0; j < 4; ++j) linv[j] = 1.f / __shfl(lrun, (l & 48) | (lh * 4 + j));
  #pragma unroll
  for (int j = 0; j < 4; ++j) {
    int q = qb * 128 + w * 16 + lh * 4 + j;
    u16* op = AO + (size_t)(b * Sc + q) * DIMc + h * Dc + ln15;
    #pragma unroll
    for (int fd = 0; fd < 8; ++fd) op[fd * 16] = f2bf(oacc[fd][j] * linv[j]);
  }
}

extern "C" void kernel_launch(void* const* d_in, const int* in_sizes, int n_in,
                              void* d_out, int out_size, void* d_ws, size_t ws_size,
                              hipStream_t stream) {
  const float* x  = (const float*)d_in[0];
  const float* wq = (const float*)d_in[1];
  const float* wk = (const float*)d_in[2];
  const float* wv = (const float*)d_in[3];
  const float* wo = (const float*)d_in[4];
  float* out = (float*)d_out;

  char* ws = (char*)d_ws;
  size_t off = 0;
  auto alloc = [&](size_t bytes) -> char* {
    char* p = ws + off;
    off += (bytes + 255) & ~(size_t)255;
    return p;
  };
  float* tbl  = (float*)alloc((size_t)Sc * 64 * 2 * 4);
  u16* xb    = (u16*)alloc((size_t)BS * DIMc * 2);     // x bf16; later reused as AO
  u16* wqT   = (u16*)alloc((size_t)4096 * 4096 * 2);   // wqT; later woT
  u16* wkvT  = (u16*)alloc((size_t)2048 * 4096 * 2);   // [wkT ; wvT]
  u16* Qb    = (u16*)alloc((size_t)BS * 4096 * 2);     // roped Q in [b][h][s][d]
  u16* Krp   = (u16*)alloc((size_t)BS * 1024 * 2);     // roped K in [b][hkv][s][d]
  u16* Vtp   = (u16*)alloc((size_t)BS * 1024 * 2);     // V in [b][hkv][d][sigma(s)]
  u16* AO = xb;    // alias: xb dead after K/V GEMM
  u16* woT = wqT;  // alias: wqT dead after Q GEMM

  rope_table_k<<<(Sc * 64) / 256, 256, 0, stream>>>(tbl);
  f32_to_bf16_k<<<(BS * DIMc / 4) / 256, 256, 0, stream>>>(x, xb, BS * DIMc / 4);

  transpose_w_k<<<dim3(64, 64), 256, 0, stream>>>(wq, wqT, 4096, 4096);
  gemm256<2><<<256, 512, 131072, stream>>>(xb, wqT, Qb, tbl, 4096, 4096, 4096);  // Q + RoPE + relayout

  transpose_w_k<<<dim3(16, 64), 256, 0, stream>>>(wk, wkvT, 4096, 1024);
  transpose_w_k<<<dim3(16, 64), 256, 0, stream>>>(wv, wkvT + (size_t)1024 * 4096, 4096, 1024);
  gemm_kv<<<256, 512, 98304, stream>>>(xb, wkvT, Krp, Vtp, tbl);                 // K+RoPE, V+sigma-transpose

  attn_k<<<dim3(8, Hc, Bc), 512, 65536, stream>>>(Qb, Krp, Vtp, AO);

  transpose_w_k<<<dim3(64, 64), 256, 0, stream>>>(wo, woT, 4096, 4096);
  gemm256<1><<<256, 512, 131072, stream>>>(AO, woT, out, tbl, 4096, 4096, 4096);
}

// Round 14
// 468.729 us; speedup vs baseline: 1.0255x; 1.0044x over previous
//
#include <hip/hip_runtime.h>

typedef unsigned short u16;
typedef unsigned int u32;
typedef __attribute__((ext_vector_type(8))) short short8_t;  // 8 bf16 (4 VGPRs)
typedef __attribute__((ext_vector_type(4))) float f32x4;

static constexpr int Bc = 4, Sc = 1024, Hc = 32, HKVc = 8, Dc = 128;
static constexpr int BS = Bc * Sc;     // 4096 rows
static constexpr int DIMc = 4096;

__device__ __forceinline__ u16 f2bf(float f) {
  u32 u = __float_as_uint(f);
  u32 r = (u + 0x7fffu + ((u >> 16) & 1u)) >> 16;  // RNE
  return (u16)r;
}
__device__ __forceinline__ float bf2f(u16 u) {
  return __uint_as_float(((u32)u) << 16);
}
__device__ __forceinline__ void gload_lds16(const void* g, void* l) {
  __builtin_amdgcn_global_load_lds((const __attribute__((address_space(1))) void*)g,
                                   (__attribute__((address_space(3))) void*)l, 16, 0, 0);
}

#define SBAR __builtin_amdgcn_sched_barrier(0)
#define PBARRIER do { SBAR; __builtin_amdgcn_s_barrier(); SBAR; } while (0)
#define WAITVM(N) asm volatile("s_waitcnt vmcnt(" #N ")" ::: "memory")

// ---------------- RoPE table: cos/sin for (s, i) ----------------
__global__ void rope_table_k(float* __restrict__ tbl) {
  int i = blockIdx.x * 256 + threadIdx.x;     // 1024*64
  int s = i >> 6, fi = i & 63;
  float freq = powf(10000.f, -(float)fi / 64.f);
  float ang = (float)s * freq;
  float sv, cv;
  sincosf(ang, &sv, &cv);
  tbl[2 * i] = cv;
  tbl[2 * i + 1] = sv;
}

// ---------------- fp32 -> bf16 convert (vectorized) ----------------
__global__ void f32_to_bf16_k(const float* __restrict__ in, u16* __restrict__ out, int n4) {
  int i = blockIdx.x * 256 + threadIdx.x;
  if (i >= n4) return;
  float4 v = *(const float4*)(in + (size_t)i * 4);
  uint2 pk;
  pk.x = (u32)f2bf(v.x) | ((u32)f2bf(v.y) << 16);
  pk.y = (u32)f2bf(v.z) | ((u32)f2bf(v.w) << 16);
  *(uint2*)(out + (size_t)i * 4) = pk;
}

// ---------------- W (K,N) fp32 -> WT (N,K) bf16, tiled transpose ----------------
__global__ __launch_bounds__(256) void transpose_w_k(const float* __restrict__ W, u16* __restrict__ WT,
                                                     int Kdim, int Ndim) {
  __shared__ float tile[64 * 65];
  const int t = threadIdx.x;
  const int n0 = blockIdx.x * 64, k0 = blockIdx.y * 64;
  #pragma unroll
  for (int p = 0; p < 4; ++p) {
    int idx = p * 256 + t;           // 1024 float4 chunks
    int r = idx >> 4, c = (idx & 15) * 4;
    float4 v = *(const float4*)(W + (size_t)(k0 + r) * Ndim + n0 + c);
    tile[r * 65 + c + 0] = v.x;
    tile[r * 65 + c + 1] = v.y;
    tile[r * 65 + c + 2] = v.z;
    tile[r * 65 + c + 3] = v.w;
  }
  __syncthreads();
  #pragma unroll
  for (int p = 0; p < 2; ++p) {
    int idx = p * 256 + t;           // 512 chunks of 8 bf16
    int n = idx >> 3, c = (idx & 7) * 8;
    alignas(16) u16 o[8];
    #pragma unroll
    for (int i = 0; i < 8; ++i) o[i] = f2bf(tile[(c + i) * 65 + n]);
    *(uint4*)(WT + (size_t)(n0 + n) * Kdim + k0 + c) = *(const uint4*)o;
  }
}

// ---------------- 256^2-tile GEMM, each-frag-once / counted-vmcnt (R11 best) ----------------
// MODE 1: f32 C row-major; MODE 2: bf16 + fused RoPE + relayout to Q[b][h][s][d].
#define MFMAQ(QI, AF, BF)                                                                \
  do {                                                                                   \
    __builtin_amdgcn_s_setprio(1);                                                       \
    _Pragma("unroll") for (int mf = 0; mf < 4; ++mf)                                     \
      _Pragma("unroll") for (int nf = 0; nf < 2; ++nf)                                   \
        _Pragma("unroll") for (int kk = 0; kk < 2; ++kk)                                 \
          acc[QI][mf][nf] = __builtin_amdgcn_mfma_f32_16x16x32_bf16(                     \
              AF[mf][kk], BF[nf][kk], acc[QI][mf][nf], 0, 0, 0);                         \
    __builtin_amdgcn_s_setprio(0);                                                       \
  } while (0)

template <int MODE>
__global__ __launch_bounds__(512, 2) void gemm256(const u16* __restrict__ A, const u16* __restrict__ BT,
                                                  void* __restrict__ Cv, const float* __restrict__ tbl,
                                                  int M, int N, int K) {
  extern __shared__ char smem[];   // 131072 B
  const int t = threadIdx.x, l = t & 63, w = t >> 6;
  const int ln15 = l & 15, lh = l >> 4;
  const int NT = K >> 6;

  int id = blockIdx.x;
  int nwg = gridDim.x;
  int swz = ((nwg & 7) == 0) ? ((id & 7) * (nwg >> 3) + (id >> 3)) : id;
  const int nbn = N >> 8;
  const int bm = swz / nbn, bn = swz % nbn;

  const u16* Ag = A + (size_t)bm * 256 * K;
  const u16* Bg = BT + (size_t)bn * 256 * K;

  f32x4 acc[4][4][2];
  #pragma unroll
  for (int q = 0; q < 4; ++q)
    #pragma unroll
    for (int mf = 0; mf < 4; ++mf)
      #pragma unroll
      for (int nf = 0; nf < 2; ++nf) acc[q][mf][nf] = f32x4{0.f, 0.f, 0.f, 0.f};
  short8_t af[4][2], af2[4][2], bfB0[2][2], bfB1[2][2];

  const int srow = (l >> 3);
  const int sck  = (l & 7) ^ srow;
  auto stageA = [&](char* bufbase, int h, int tt) {
    char* lb = bufbase + h * 16384 + w * 1024;
    const u16* g = Ag + (size_t)(h * 128 + w * 8 + srow) * K + tt * 64 + (sck << 3);
    gload_lds16(g, lb);
    gload_lds16(g + (size_t)64 * K, lb + 8192);
  };
  auto stageB = [&](char* bufbase, int h, int tt) {
    char* lb = bufbase + 32768 + h * 16384 + w * 1024;
    const u16* g = Bg + (size_t)(h * 128 + w * 8 + srow) * K + tt * 64 + (sck << 3);
    gload_lds16(g, lb);
    gload_lds16(g + (size_t)64 * K, lb + 8192);
  };
  const int arow = (w >> 2) * 64 + ln15;
  const int brow = (w & 3) * 32 + ln15;
  const int rsw = ln15 & 7;
  auto LDA = [&](const char* cb, int qm, short8_t (&dst)[4][2]) {
    #pragma unroll
    for (int mf = 0; mf < 4; ++mf)
      #pragma unroll
      for (int kk = 0; kk < 2; ++kk)
        dst[mf][kk] = *(const short8_t*)(cb + qm * 16384 + (arow + mf * 16) * 128 +
                                         (((kk * 4 + lh) ^ rsw) << 4));
  };
  auto LDB = [&](const char* cb, int qn, short8_t (&dst)[2][2]) {
    #pragma unroll
    for (int nf = 0; nf < 2; ++nf)
      #pragma unroll
      for (int kk = 0; kk < 2; ++kk)
        dst[nf][kk] = *(const short8_t*)(cb + 32768 + qn * 16384 + (brow + nf * 16) * 128 +
                                         (((kk * 4 + lh) ^ rsw) << 4));
  };

  // ---- prologue: stage tile 0 (A0,B0,B1,A1); retire all but A1 ----
  stageA(smem, 0, 0);
  stageB(smem, 0, 0);
  stageB(smem, 1, 0);
  stageA(smem, 1, 0);
  WAITVM(2);
  PBARRIER;

  for (int T = 0; T < NT; ++T) {
    char* cb = smem + (T & 1) * 65536;
    char* nb = smem + ((T & 1) ^ 1) * 65536;
    const bool s1 = (T + 1 < NT);
    // resident B for this tile (cb valid post-barrier except A1, handled below)
    LDB(cb, 0, bfB0);
    LDB(cb, 1, bfB1);
    // stage ALL of T+1 now (order A0,B0,B1,A1) -> full-tile latency lead
    if (s1) {
      stageA(nb, 0, T + 1);
      stageB(nb, 0, T + 1);
      stageB(nb, 1, T + 1);
      stageA(nb, 1, T + 1);
    }
    // p1: A0 phase
    LDA(cb, 0, af);
    MFMAQ(0, af, bfB0);     // Q00
    MFMAQ(3, af, bfB1);     // Q01
    // p2: A1 phase (A1(T) retired: it was issued one tile ago)
    if (s1) { WAITVM(8); } else { WAITVM(0); }
    LDA(cb, 1, af2);
    MFMAQ(1, af2, bfB0);    // Q10
    MFMAQ(2, af2, bfB1);    // Q11
    if (s1) { WAITVM(2); }  // retire A0,B0,B1 of T+1; keep A1(T+1) in flight
    PBARRIER;               // all waves done reading cb; nb (minus A1) valid
  }

  // ---- epilogue ----
  const int rw = (w >> 2) * 64, cw = (w & 3) * 32;
  #pragma unroll
  for (int qi = 0; qi < 4; ++qi) {
    const int qm = (qi == 1 || qi == 2) ? 1 : 0;
    const int qn = (qi >= 2) ? 1 : 0;
    #pragma unroll
    for (int mf = 0; mf < 4; ++mf)
      #pragma unroll
      for (int nf = 0; nf < 2; ++nf)
        #pragma unroll
        for (int e = 0; e < 4; ++e) {
          int row = bm * 256 + qm * 128 + rw + mf * 16 + lh * 4 + e;
          int col = bn * 256 + qn * 128 + cw + nf * 16 + ln15;
          float v = acc[qi][mf][nf][e];
          if (MODE == 2) {
            float pv = __shfl_xor(v, 1);        // partner holds col^1 (same row)
            int d = col & 127, hh = col >> 7;
            int s = row & (Sc - 1), bb = row >> 10;
            float2 cs = *(const float2*)(tbl + (size_t)(s * 64 + (d >> 1)) * 2);
            float o = (d & 1) ? (v * cs.x + pv * cs.y) : (v * cs.x - pv * cs.y);
            o *= 0.08838834764831845f;
            ((u16*)Cv)[(((size_t)(bb * Hc + hh) * Sc + s) << 7) + d] = f2bf(o);
          } else {
            size_t idx = (size_t)row * N + col;
            ((float*)Cv)[idx] = v;
          }
        }
  }
}

// ---------------- Fused K+V projection GEMM, BM=128 x BN=256 ----------------
#define MFMAKV(PH, BF)                                                                   \
  do {                                                                                   \
    __builtin_amdgcn_s_setprio(1);                                                       \
    _Pragma("unroll") for (int mf = 0; mf < 4; ++mf)                                     \
      _Pragma("unroll") for (int nf = 0; nf < 2; ++nf)                                   \
        _Pragma("unroll") for (int kk = 0; kk < 2; ++kk)                                 \
          acc[mf][(PH) * 2 + nf] = __builtin_amdgcn_mfma_f32_16x16x32_bf16(              \
              af[mf][kk], BF[nf][kk], acc[mf][(PH) * 2 + nf], 0, 0, 0);                  \
    __builtin_amdgcn_s_setprio(0);                                                       \
  } while (0)

__global__ __launch_bounds__(512, 1) void gemm_kv(const u16* __restrict__ A, const u16* __restrict__ BT,
                                                  u16* __restrict__ Krp, u16* __restrict__ Vtp,
                                                  const float* __restrict__ tbl) {
  extern __shared__ char smem[];   // A dbuf 2x16KB @0 | B dbuf 2x32KB @32768 = 98304 B
  const int t = threadIdx.x, l = t & 63, w = t >> 6;
  const int ln15 = l & 15, lh = l >> 4;
  const int K = 4096, NT = 64;

  int id = blockIdx.x;
  int swz = (id & 7) * 32 + (id >> 3);      // 256 blocks, XCD-bijective
  const int bm = swz >> 3, bn = swz & 7;    // 32 x 8

  const u16* Ag = A + (size_t)bm * 128 * K;
  const u16* Bg = BT + (size_t)bn * 256 * K;

  f32x4 acc[4][4];
  #pragma unroll
  for (int mf = 0; mf < 4; ++mf)
    #pragma unroll
    for (int nf = 0; nf < 4; ++nf) acc[mf][nf] = f32x4{0.f, 0.f, 0.f, 0.f};
  short8_t af[4][2], bfL[2][2], bfR[2][2];

  const int srow = (l >> 3);
  const int sck  = (l & 7) ^ srow;
  auto stageA = [&](int buf, int tt) {          // A tile = 128 rows x 64 K = 16KB
    char* lb = smem + buf * 16384 + w * 1024;
    const u16* g = Ag + (size_t)(w * 8 + srow) * K + tt * 64 + (sck << 3);
    gload_lds16(g, lb);
    gload_lds16(g + (size_t)64 * K, lb + 8192);
  };
  auto stageB = [&](int buf, int h, int tt) {   // one B half = 128 rows x 64 K = 16KB
    char* lb = smem + 32768 + buf * 32768 + h * 16384 + w * 1024;
    const u16* g = Bg + (size_t)(h * 128 + w * 8 + srow) * K + tt * 64 + (sck << 3);
    gload_lds16(g, lb);
    gload_lds16(g + (size_t)64 * K, lb + 8192);
  };
  const int arow = (w >> 2) * 64 + ln15;        // 0..127 within A tile
  const int bcol0 = (w & 3) * 64;               // wave's B col group (4 nf x 16)
  const int rsw = ln15 & 7;
  auto LDA = [&](int buf) {
    #pragma unroll
    for (int mf = 0; mf < 4; ++mf)
      #pragma unroll
      for (int kk = 0; kk < 2; ++kk)
        af[mf][kk] = *(const short8_t*)(smem + buf * 16384 + (arow + mf * 16) * 128 +
                                        (((kk * 4 + lh) ^ rsw) << 4));
  };
  auto LDB = [&](int buf, int half, short8_t (&dst)[2][2]) {
    #pragma unroll
    for (int nf = 0; nf < 2; ++nf)
      #pragma unroll
      for (int kk = 0; kk < 2; ++kk) {
        int brow = bcol0 + (half * 2 + nf) * 16 + ln15;   // 0..255
        dst[nf][kk] = *(const short8_t*)(smem + 32768 + buf * 32768 + brow * 128 +
                                         (((kk * 4 + lh) ^ rsw) << 4));
      }
  };

  // prologue: stage tile 0 (A, B0, B1); retire A,B0 (B1 stays in flight)
  stageA(0, 0);
  stageB(0, 0, 0);
  stageB(0, 1, 0);
  WAITVM(2);
  PBARRIER;

  for (int T = 0; T < NT; ++T) {
    const int cb = T & 1, nb = cb ^ 1;
    const bool st = (T + 1 < NT);
    LDA(cb);                 // A resident for the tile
    LDB(cb, 0, bfL);
    if (st) { stageA(nb, T + 1); stageB(nb, 0, T + 1); stageB(nb, 1, T + 1); }
    // p1: left B half
    MFMAKV(0, bfL);
    if (st) { WAITVM(6); } else { WAITVM(0); }   // retire B1(T)
    LDB(cb, 1, bfR);
    // p2: right B half
    MFMAKV(1, bfR);
    if (st) { WAITVM(2); }                       // retire A,B0(T+1); keep B1(T+1)
    PBARRIER;
  }

  // epilogue
  #pragma unroll
  for (int mf = 0; mf < 4; ++mf)
    #pragma unroll
    for (int nf = 0; nf < 4; ++nf)
      #pragma unroll
      for (int e = 0; e < 4; ++e) {
        int row = bm * 128 + (w >> 2) * 64 + mf * 16 + lh * 4 + e;
        int col = bn * 256 + bcol0 + nf * 16 + ln15;
        float v = acc[mf][nf][e];
        float pv = __shfl_xor(v, 1);
        int s = row & (Sc - 1), bb = row >> 10;
        if (col < 1024) {          // K + RoPE
          int hkv = col >> 7, d = col & 127;
          float2 cs = *(const float2*)(tbl + (size_t)(s * 64 + (d >> 1)) * 2);
          float o = (d & 1) ? (v * cs.x + pv * cs.y) : (v * cs.x - pv * cs.y);
          Krp[(((size_t)(bb * HKVc + hkv) * Sc + s) << 7) + d] = f2bf(o);
        } else {                   // V, sigma-permuted transpose
          int vc = col - 1024;
          int hkv = vc >> 7, d = vc & 127;
          int sl = s & 63;
          int sg = (sl & 32) | (((sl >> 2) & 3) << 3) | (((sl >> 4) & 1) << 2) | (sl & 3);
          Vtp[((size_t)(bb * HKVc + hkv) * Dc + d) * Sc + (s & ~63) + sg] = f2bf(v);
        }
      }
}

// ---------------- Flash attention (causal, GQA), swapped-QK^T, P in registers ----------------
// 4 waves x 32 q-rows (2 groups of 16). K/V fragment reads shared across both
// groups -> LDS read amplification halved vs 8-wave/16-row version.
__global__ __launch_bounds__(256, 2) void attn_k(const u16* __restrict__ Q, const u16* __restrict__ Kr,
                                                 const u16* __restrict__ Vt, u16* __restrict__ AO) {
  extern __shared__ char smem[];
  const int t = threadIdx.x, l = t & 63, w = t >> 6;   // w in 0..3
  const int qb = (int)gridDim.x - 1 - (int)blockIdx.x;   // big causal tiles first
  const int h = blockIdx.y, b = blockIdx.z;
  const int hkv = h >> 2;
  const int ln15 = l & 15, lh = l >> 4;
  const int NT = 2 * qb + 2;

  const u16* Kg0 = Kr + (size_t)(b * HKVc + hkv) * Sc * Dc;
  const u16* Vg0 = Vt + (size_t)(b * HKVc + hkv) * Dc * Sc;

  auto stageK = [&](int buf, int tt) {      // 64 rows x 128 d; wave stages 16 rows
    char* base = smem + buf * 16384 + w * 4096;
    #pragma unroll
    for (int i = 0; i < 4; ++i) {
      int row = w * 16 + i * 4 + (l >> 4);
      int c = l & 15;
      gload_lds16(Kg0 + (size_t)(tt * 64 + row) * Dc + ((c ^ (row & 7)) << 3), base + i * 1024);
    }
  };
  auto stageV = [&](int buf, int tt) {      // 128 d x 64 kv; wave stages 32 d-rows
    char* base = smem + 32768 + buf * 16384 + w * 4096;
    #pragma unroll
    for (int i = 0; i < 4; ++i) {
      int d = w * 32 + i * 8 + (l >> 3);
      int c = l & 7;
      gload_lds16(Vg0 + (size_t)d * Sc + tt * 64 + ((c ^ (d & 7)) << 3), base + i * 1024);
    }
  };

  // Q fragments: 2 groups of 16 q-rows per wave
  short8_t qf[2][4];
  #pragma unroll
  for (int g = 0; g < 2; ++g) {
    int q = qb * 128 + w * 32 + g * 16 + ln15;
    const u16* qp = Q + ((size_t)(b * Hc + h) * Sc + q) * Dc + lh * 8;
    #pragma unroll
    for (int ks = 0; ks < 4; ++ks) qf[g][ks] = *(const short8_t*)(qp + ks * 32);
  }
  SBAR;   // qf loads issued before staging (vmcnt ordering)

  f32x4 oacc[2][8];
  #pragma unroll
  for (int g = 0; g < 2; ++g)
    #pragma unroll
    for (int i = 0; i < 8; ++i) oacc[g][i] = f32x4{0.f, 0.f, 0.f, 0.f};
  float mrun[2] = {-1e30f, -1e30f}, lrun[2] = {0.f, 0.f};

  stageK(0, 0); stageV(0, 0);
  stageK(1, 1); stageV(1, 1);

  const int qmaxw = qb * 128 + w * 32 + 31;

  for (int T = 0; T < NT; ++T) {
    if (T < NT - 1) { WAITVM(8); } else { WAITVM(0); }
    PBARRIER;
    const char* Kb = smem + (T & 1) * 16384;
    const char* Vb = smem + 32768 + (T & 1) * 16384;

    if (T * 64 <= qmaxw) {     // both groups active together (32-aligned offsets)
      // S^T = K.Q^T per group; kf shared across groups
      f32x4 sf[2][4];
      #pragma unroll
      for (int fc = 0; fc < 4; ++fc) {
        sf[0][fc] = f32x4{0.f, 0.f, 0.f, 0.f};
        sf[1][fc] = f32x4{0.f, 0.f, 0.f, 0.f};
        int kvr = fc * 16 + ln15;
        #pragma unroll
        for (int ks = 0; ks < 4; ++ks) {
          int chunk = ks * 4 + lh;
          short8_t kf = *(const short8_t*)(Kb + kvr * 256 + ((chunk ^ (kvr & 7)) << 4));
          sf[0][fc] = __builtin_amdgcn_mfma_f32_16x16x32_bf16(kf, qf[0][ks], sf[0][fc], 0, 0, 0);
          sf[1][fc] = __builtin_amdgcn_mfma_f32_16x16x32_bf16(kf, qf[1][ks], sf[1][fc], 0, 0, 0);
        }
      }
      if (T * 64 + 63 > qb * 128 + w * 32) {   // diagonal overlap: mask kv > q per group
        #pragma unroll
        for (int g = 0; g < 2; ++g) {
          int qlane = qb * 128 + w * 32 + g * 16 + ln15;
          #pragma unroll
          for (int fc = 0; fc < 4; ++fc)
            #pragma unroll
            for (int j = 0; j < 4; ++j) {
              int kvg = T * 64 + fc * 16 + lh * 4 + j;
              if (kvg > qlane) sf[g][fc][j] = -1e30f;
            }
        }
      }
      // online softmax per group
      short8_t pa[2][2];
      #pragma unroll
      for (int g = 0; g < 2; ++g) {
        float mx = sf[g][0][0];
        #pragma unroll
        for (int fc = 0; fc < 4; ++fc)
          #pragma unroll
          for (int j = 0; j < 4; ++j) mx = fmaxf(mx, sf[g][fc][j]);
        mx = fmaxf(mx, __shfl_xor(mx, 16));
        mx = fmaxf(mx, __shfl_xor(mx, 32));
        float mnew = fmaxf(mrun[g], mx);
        float alpha = __expf(mrun[g] - mnew);
        mrun[g] = mnew;
        float rs = 0.f;
        #pragma unroll
        for (int fc = 0; fc < 4; ++fc)
          #pragma unroll
          for (int j = 0; j < 4; ++j) {
            float p = __expf(sf[g][fc][j] - mnew);
            sf[g][fc][j] = p;
            rs += p;
          }
        rs += __shfl_xor(rs, 16);
        rs += __shfl_xor(rs, 32);
        lrun[g] = lrun[g] * alpha + rs;
        float arow[4];
        #pragma unroll
        for (int j = 0; j < 4; ++j) arow[j] = __shfl(alpha, (l & 48) | (lh * 4 + j));
        #pragma unroll
        for (int fd = 0; fd < 8; ++fd)
          #pragma unroll
          for (int j = 0; j < 4; ++j) oacc[g][fd][j] *= arow[j];
        #pragma unroll
        for (int ks = 0; ks < 2; ++ks)
          #pragma unroll
          for (int b2 = 0; b2 < 2; ++b2)
            #pragma unroll
            for (int j = 0; j < 4; ++j) pa[g][ks][b2 * 4 + j] = (short)f2bf(sf[g][ks * 2 + b2][j]);
      }
      // PV: vf shared across groups
      #pragma unroll
      for (int fd = 0; fd < 8; ++fd) {
        int dcol = fd * 16 + ln15;
        #pragma unroll
        for (int ks = 0; ks < 2; ++ks) {
          int chunk = ks * 4 + lh;
          short8_t vf = *(const short8_t*)(Vb + dcol * 128 + ((chunk ^ (dcol & 7)) << 4));
          oacc[0][fd] = __builtin_amdgcn_mfma_f32_16x16x32_bf16(pa[0][ks], vf, oacc[0][fd], 0, 0, 0);
          oacc[1][fd] = __builtin_amdgcn_mfma_f32_16x16x32_bf16(pa[1][ks], vf, oacc[1][fd], 0, 0, 0);
        }
      }
    }
    PBARRIER;
    if (T + 2 < NT) { stageK(T & 1, T + 2); stageV(T & 1, T + 2); }
  }

  // epilogue per group: O /= l, write [b][s][h*128+d]
  #pragma unroll
  for (int g = 0; g < 2; ++g) {
    float linv[4];
    #pragma unroll
    for (int j = 0; j < 4; ++j) linv[j] = 1.f / __shfl(lrun[g], (l & 48) | (lh * 4 + j));
    #pragma unroll
    for (int j = 0; j < 4; ++j) {
      int q = qb * 128 + w * 32 + g * 16 + lh * 4 + j;
      u16* op = AO + (size_t)(b * Sc + q) * DIMc + h * Dc + ln15;
      #pragma unroll
      for (int fd = 0; fd < 8; ++fd) op[fd * 16] = f2bf(oacc[g][fd][j] * linv[j]);
    }
  }
}

extern "C" void kernel_launch(void* const* d_in, const int* in_sizes, int n_in,
                              void* d_out, int out_size, void* d_ws, size_t ws_size,
                              hipStream_t stream) {
  const float* x  = (const float*)d_in[0];
  const float* wq = (const float*)d_in[1];
  const float* wk = (const float*)d_in[2];
  const float* wv = (const float*)d_in[3];
  const float* wo = (const float*)d_in[4];
  float* out = (float*)d_out;

  char* ws = (char*)d_ws;
  size_t off = 0;
  auto alloc = [&](size_t bytes) -> char* {
    char* p = ws + off;
    off += (bytes + 255) & ~(size_t)255;
    return p;
  };
  float* tbl  = (float*)alloc((size_t)Sc * 64 * 2 * 4);
  u16* xb    = (u16*)alloc((size_t)BS * DIMc * 2);     // x bf16; later reused as AO
  u16* wqT   = (u16*)alloc((size_t)4096 * 4096 * 2);   // wqT; later woT
  u16* wkvT  = (u16*)alloc((size_t)2048 * 4096 * 2);   // [wkT ; wvT]
  u16* Qb    = (u16*)alloc((size_t)BS * 4096 * 2);     // roped Q in [b][h][s][d]
  u16* Krp   = (u16*)alloc((size_t)BS * 1024 * 2);     // roped K in [b][hkv][s][d]
  u16* Vtp   = (u16*)alloc((size_t)BS * 1024 * 2);     // V in [b][hkv][d][sigma(s)]
  u16* AO = xb;    // alias: xb dead after K/V GEMM
  u16* woT = wqT;  // alias: wqT dead after Q GEMM

  rope_table_k<<<(Sc * 64) / 256, 256, 0, stream>>>(tbl);
  f32_to_bf16_k<<<(BS * DIMc / 4) / 256, 256, 0, stream>>>(x, xb, BS * DIMc / 4);

  transpose_w_k<<<dim3(64, 64), 256, 0, stream>>>(wq, wqT, 4096, 4096);
  gemm256<2><<<256, 512, 131072, stream>>>(xb, wqT, Qb, tbl, 4096, 4096, 4096);  // Q + RoPE + relayout

  transpose_w_k<<<dim3(16, 64), 256, 0, stream>>>(wk, wkvT, 4096, 1024);
  transpose_w_k<<<dim3(16, 64), 256, 0, stream>>>(wv, wkvT + (size_t)1024 * 4096, 4096, 1024);
  gemm_kv<<<256, 512, 98304, stream>>>(xb, wkvT, Krp, Vtp, tbl);                 // K+RoPE, V+sigma-transpose

  attn_k<<<dim3(8, Hc, Bc), 256, 65536, stream>>>(Qb, Krp, Vtp, AO);

  transpose_w_k<<<dim3(64, 64), 256, 0, stream>>>(wo, woT, 4096, 4096);
  gemm256<1><<<256, 512, 131072, stream>>>(AO, woT, out, tbl, 4096, 4096, 4096);
}

// Round 15
// 466.274 us; speedup vs baseline: 1.0309x; 1.0053x over previous
//
#include <hip/hip_runtime.h>

typedef unsigned short u16;
typedef unsigned int u32;
typedef __attribute__((ext_vector_type(8))) short short8_t;  // 8 bf16 (4 VGPRs)
typedef __attribute__((ext_vector_type(4))) float f32x4;

static constexpr int Bc = 4, Sc = 1024, Hc = 32, HKVc = 8, Dc = 128;
static constexpr int BS = Bc * Sc;     // 4096 rows
static constexpr int DIMc = 4096;

__device__ __forceinline__ u16 f2bf(float f) {
  u32 u = __float_as_uint(f);
  u32 r = (u + 0x7fffu + ((u >> 16) & 1u)) >> 16;  // RNE
  return (u16)r;
}
__device__ __forceinline__ float bf2f(u16 u) {
  return __uint_as_float(((u32)u) << 16);
}
__device__ __forceinline__ void gload_lds16(const void* g, void* l) {
  __builtin_amdgcn_global_load_lds((const __attribute__((address_space(1))) void*)g,
                                   (__attribute__((address_space(3))) void*)l, 16, 0, 0);
}

#define SBAR __builtin_amdgcn_sched_barrier(0)
#define PBARRIER do { SBAR; __builtin_amdgcn_s_barrier(); SBAR; } while (0)
#define WAITVM(N) asm volatile("s_waitcnt vmcnt(" #N ")" ::: "memory")

// ---------------- RoPE table: cos/sin for (s, i) ----------------
__global__ void rope_table_k(float* __restrict__ tbl) {
  int i = blockIdx.x * 256 + threadIdx.x;     // 1024*64
  int s = i >> 6, fi = i & 63;
  float freq = powf(10000.f, -(float)fi / 64.f);
  float ang = (float)s * freq;
  float sv, cv;
  sincosf(ang, &sv, &cv);
  tbl[2 * i] = cv;
  tbl[2 * i + 1] = sv;
}

// ---------------- fp32 -> bf16 convert (vectorized) ----------------
__global__ void f32_to_bf16_k(const float* __restrict__ in, u16* __restrict__ out, int n4) {
  int i = blockIdx.x * 256 + threadIdx.x;
  if (i >= n4) return;
  float4 v = *(const float4*)(in + (size_t)i * 4);
  uint2 pk;
  pk.x = (u32)f2bf(v.x) | ((u32)f2bf(v.y) << 16);
  pk.y = (u32)f2bf(v.z) | ((u32)f2bf(v.w) << 16);
  *(uint2*)(out + (size_t)i * 4) = pk;
}

// ---------------- W (K,N) fp32 -> WT (N,K) bf16, tiled transpose ----------------
__global__ __launch_bounds__(256) void transpose_w_k(const float* __restrict__ W, u16* __restrict__ WT,
                                                     int Kdim, int Ndim) {
  __shared__ float tile[64 * 65];
  const int t = threadIdx.x;
  const int n0 = blockIdx.x * 64, k0 = blockIdx.y * 64;
  #pragma unroll
  for (int p = 0; p < 4; ++p) {
    int idx = p * 256 + t;           // 1024 float4 chunks
    int r = idx >> 4, c = (idx & 15) * 4;
    float4 v = *(const float4*)(W + (size_t)(k0 + r) * Ndim + n0 + c);
    tile[r * 65 + c + 0] = v.x;
    tile[r * 65 + c + 1] = v.y;
    tile[r * 65 + c + 2] = v.z;
    tile[r * 65 + c + 3] = v.w;
  }
  __syncthreads();
  #pragma unroll
  for (int p = 0; p < 2; ++p) {
    int idx = p * 256 + t;           // 512 chunks of 8 bf16
    int n = idx >> 3, c = (idx & 7) * 8;
    alignas(16) u16 o[8];
    #pragma unroll
    for (int i = 0; i < 8; ++i) o[i] = f2bf(tile[(c + i) * 65 + n]);
    *(uint4*)(WT + (size_t)(n0 + n) * Kdim + k0 + c) = *(const uint4*)o;
  }
}

// ---------------- 256^2-tile GEMM, m201-faithful 4-phase schedule ----------------
// MODE 1: f32 C row-major; MODE 2: bf16 + fused RoPE + relayout to Q[b][h][s][d].
// Per K-tile: 4 phases, each {frag ds_reads + 1 half-tile stage -> s_barrier ->
// 16 MFMA (setprio)} with NO post-MFMA barrier: a wave finishing its MFMA
// cluster immediately issues the next phase's ds_reads, overlapping slower
// waves' MFMAs (the m196/m201 lever). Each fragment read once (12/8/4/0).
// Stage targets the region freed the previous phase; single vmcnt(6) per tile
// at ph4 (3 half-tiles in flight; never 0 until the tail).
#define MFMAQ(QI, AF, BF)                                                                \
  do {                                                                                   \
    __builtin_amdgcn_s_setprio(1);                                                       \
    _Pragma("unroll") for (int mf = 0; mf < 4; ++mf)                                     \
      _Pragma("unroll") for (int nf = 0; nf < 2; ++nf)                                   \
        _Pragma("unroll") for (int kk = 0; kk < 2; ++kk)                                 \
          acc[QI][mf][nf] = __builtin_amdgcn_mfma_f32_16x16x32_bf16(                     \
              AF[mf][kk], BF[nf][kk], acc[QI][mf][nf], 0, 0, 0);                         \
    __builtin_amdgcn_s_setprio(0);                                                       \
  } while (0)

template <int MODE>
__global__ __launch_bounds__(512, 2) void gemm256(const u16* __restrict__ A, const u16* __restrict__ BT,
                                                  void* __restrict__ Cv, const float* __restrict__ tbl,
                                                  int M, int N, int K) {
  extern __shared__ char smem[];   // 131072 B
  const int t = threadIdx.x, l = t & 63, w = t >> 6;
  const int ln15 = l & 15, lh = l >> 4;
  const int NT = K >> 6;

  int id = blockIdx.x;
  int nwg = gridDim.x;
  int swz = ((nwg & 7) == 0) ? ((id & 7) * (nwg >> 3) + (id >> 3)) : id;
  const int nbn = N >> 8;
  const int bm = swz / nbn, bn = swz % nbn;

  const u16* Ag = A + (size_t)bm * 256 * K;
  const u16* Bg = BT + (size_t)bn * 256 * K;

  f32x4 acc[4][4][2];
  #pragma unroll
  for (int q = 0; q < 4; ++q)
    #pragma unroll
    for (int mf = 0; mf < 4; ++mf)
      #pragma unroll
      for (int nf = 0; nf < 2; ++nf) acc[q][mf][nf] = f32x4{0.f, 0.f, 0.f, 0.f};
  short8_t af[4][2], af2[4][2], bfB0[2][2], bfB1[2][2];

  const int srow = (l >> 3);
  const int sck  = (l & 7) ^ srow;
  auto stageA = [&](char* bufbase, int h, int tt) {
    char* lb = bufbase + h * 16384 + w * 1024;
    const u16* g = Ag + (size_t)(h * 128 + w * 8 + srow) * K + tt * 64 + (sck << 3);
    gload_lds16(g, lb);
    gload_lds16(g + (size_t)64 * K, lb + 8192);
  };
  auto stageB = [&](char* bufbase, int h, int tt) {
    char* lb = bufbase + 32768 + h * 16384 + w * 1024;
    const u16* g = Bg + (size_t)(h * 128 + w * 8 + srow) * K + tt * 64 + (sck << 3);
    gload_lds16(g, lb);
    gload_lds16(g + (size_t)64 * K, lb + 8192);
  };
  const int arow = (w >> 2) * 64 + ln15;
  const int brow = (w & 3) * 32 + ln15;
  const int rsw = ln15 & 7;
  auto LDA = [&](const char* cb, int qm, short8_t (&dst)[4][2]) {
    #pragma unroll
    for (int mf = 0; mf < 4; ++mf)
      #pragma unroll
      for (int kk = 0; kk < 2; ++kk)
        dst[mf][kk] = *(const short8_t*)(cb + qm * 16384 + (arow + mf * 16) * 128 +
                                         (((kk * 4 + lh) ^ rsw) << 4));
  };
  auto LDB = [&](const char* cb, int qn, short8_t (&dst)[2][2]) {
    #pragma unroll
    for (int nf = 0; nf < 2; ++nf)
      #pragma unroll
      for (int kk = 0; kk < 2; ++kk)
        dst[nf][kk] = *(const short8_t*)(cb + 32768 + qn * 16384 + (brow + nf * 16) * 128 +
                                         (((kk * 4 + lh) ^ rsw) << 4));
  };

  // ---- prologue: tile 0 fully + A0,B0,A1 of tile 1 (14 loads); retire tile 0 ----
  {
    char* b0 = smem;
    char* b1 = smem + 65536;
    stageA(b0, 0, 0); stageB(b0, 0, 0); stageA(b0, 1, 0); stageB(b0, 1, 0);
    stageA(b1, 0, 1); stageB(b1, 0, 1); stageA(b1, 1, 1);
  }
  WAITVM(6);    // tile 0 retired; {A0,B0,A1}(1) in flight
  PBARRIER;

  for (int T = 0; T < NT; ++T) {
    char* cb = smem + (T & 1) * 65536;
    char* nb = smem + ((T & 1) ^ 1) * 65536;
    const bool s1 = (T + 1 < NT), s2 = (T + 2 < NT);
    // ph1: Q00 reads A0(8)+B0(4); stage B1(T+1) -> nb (nb.B1 last read ph3(T-1))
    LDA(cb, 0, af); LDB(cb, 0, bfB0);
    if (s1) stageB(nb, 1, T + 1);
    PBARRIER;
    MFMAQ(0, af, bfB0);
    // ph2: Q10 reads A1(8); stage A0(T+2) -> cb (cb.A0 freed after ph1)
    LDA(cb, 1, af2);
    if (s2) stageA(cb, 0, T + 2);
    PBARRIER;
    MFMAQ(1, af2, bfB0);
    // ph3: Q11 reads B1(4); stage B0(T+2) -> cb (cb.B0 freed after ph1/2)
    LDB(cb, 1, bfB1);
    if (s2) stageB(cb, 0, T + 2);
    PBARRIER;
    MFMAQ(2, af2, bfB1);
    // ph4: Q01 no reads; stage A1(T+2) -> cb (freed after ph3); counted vmcnt
    if (s2) { stageA(cb, 1, T + 2); WAITVM(6); }
    else if (s1) { WAITVM(0); }       // tail: drain before final tile
    PBARRIER;
    MFMAQ(3, af, bfB1);
  }

  // ---- epilogue ----
  const int rw = (w >> 2) * 64, cw = (w & 3) * 32;
  #pragma unroll
  for (int qi = 0; qi < 4; ++qi) {
    const int qm = (qi == 1 || qi == 2) ? 1 : 0;
    const int qn = (qi >= 2) ? 1 : 0;
    #pragma unroll
    for (int mf = 0; mf < 4; ++mf)
      #pragma unroll
      for (int nf = 0; nf < 2; ++nf)
        #pragma unroll
        for (int e = 0; e < 4; ++e) {
          int row = bm * 256 + qm * 128 + rw + mf * 16 + lh * 4 + e;
          int col = bn * 256 + qn * 128 + cw + nf * 16 + ln15;
          float v = acc[qi][mf][nf][e];
          if (MODE == 2) {
            float pv = __shfl_xor(v, 1);        // partner holds col^1 (same row)
            int d = col & 127, hh = col >> 7;
            int s = row & (Sc - 1), bb = row >> 10;
            float2 cs = *(const float2*)(tbl + (size_t)(s * 64 + (d >> 1)) * 2);
            float o = (d & 1) ? (v * cs.x + pv * cs.y) : (v * cs.x - pv * cs.y);
            o *= 0.08838834764831845f;
            ((u16*)Cv)[(((size_t)(bb * Hc + hh) * Sc + s) << 7) + d] = f2bf(o);
          } else {
            size_t idx = (size_t)row * N + col;
            ((float*)Cv)[idx] = v;
          }
        }
  }
}

// ---------------- Fused K+V projection GEMM, BM=128 x BN=256 ----------------
#define MFMAKV(PH, BF)                                                                   \
  do {                                                                                   \
    __builtin_amdgcn_s_setprio(1);                                                       \
    _Pragma("unroll") for (int mf = 0; mf < 4; ++mf)                                     \
      _Pragma("unroll") for (int nf = 0; nf < 2; ++nf)                                   \
        _Pragma("unroll") for (int kk = 0; kk < 2; ++kk)                                 \
          acc[mf][(PH) * 2 + nf] = __builtin_amdgcn_mfma_f32_16x16x32_bf16(              \
              af[mf][kk], BF[nf][kk], acc[mf][(PH) * 2 + nf], 0, 0, 0);                  \
    __builtin_amdgcn_s_setprio(0);                                                       \
  } while (0)

__global__ __launch_bounds__(512, 1) void gemm_kv(const u16* __restrict__ A, const u16* __restrict__ BT,
                                                  u16* __restrict__ Krp, u16* __restrict__ Vtp,
                                                  const float* __restrict__ tbl) {
  extern __shared__ char smem[];   // A dbuf 2x16KB @0 | B dbuf 2x32KB @32768 = 98304 B
  const int t = threadIdx.x, l = t & 63, w = t >> 6;
  const int ln15 = l & 15, lh = l >> 4;
  const int K = 4096, NT = 64;

  int id = blockIdx.x;
  int swz = (id & 7) * 32 + (id >> 3);      // 256 blocks, XCD-bijective
  const int bm = swz >> 3, bn = swz & 7;    // 32 x 8

  const u16* Ag = A + (size_t)bm * 128 * K;
  const u16* Bg = BT + (size_t)bn * 256 * K;

  f32x4 acc[4][4];
  #pragma unroll
  for (int mf = 0; mf < 4; ++mf)
    #pragma unroll
    for (int nf = 0; nf < 4; ++nf) acc[mf][nf] = f32x4{0.f, 0.f, 0.f, 0.f};
  short8_t af[4][2], bfL[2][2], bfR[2][2];

  const int srow = (l >> 3);
  const int sck  = (l & 7) ^ srow;
  auto stageA = [&](int buf, int tt) {          // A tile = 128 rows x 64 K = 16KB
    char* lb = smem + buf * 16384 + w * 1024;
    const u16* g = Ag + (size_t)(w * 8 + srow) * K + tt * 64 + (sck << 3);
    gload_lds16(g, lb);
    gload_lds16(g + (size_t)64 * K, lb + 8192);
  };
  auto stageB = [&](int buf, int h, int tt) {   // one B half = 128 rows x 64 K = 16KB
    char* lb = smem + 32768 + buf * 32768 + h * 16384 + w * 1024;
    const u16* g = Bg + (size_t)(h * 128 + w * 8 + srow) * K + tt * 64 + (sck << 3);
    gload_lds16(g, lb);
    gload_lds16(g + (size_t)64 * K, lb + 8192);
  };
  const int arow = (w >> 2) * 64 + ln15;        // 0..127 within A tile
  const int bcol0 = (w & 3) * 64;               // wave's B col group (4 nf x 16)
  const int rsw = ln15 & 7;
  auto LDA = [&](int buf) {
    #pragma unroll
    for (int mf = 0; mf < 4; ++mf)
      #pragma unroll
      for (int kk = 0; kk < 2; ++kk)
        af[mf][kk] = *(const short8_t*)(smem + buf * 16384 + (arow + mf * 16) * 128 +
                                        (((kk * 4 + lh) ^ rsw) << 4));
  };
  auto LDB = [&](int buf, int half, short8_t (&dst)[2][2]) {
    #pragma unroll
    for (int nf = 0; nf < 2; ++nf)
      #pragma unroll
      for (int kk = 0; kk < 2; ++kk) {
        int brow = bcol0 + (half * 2 + nf) * 16 + ln15;   // 0..255
        dst[nf][kk] = *(const short8_t*)(smem + 32768 + buf * 32768 + brow * 128 +
                                         (((kk * 4 + lh) ^ rsw) << 4));
      }
  };

  // prologue: stage tile 0 (A, B0, B1); retire A,B0 (B1 stays in flight)
  stageA(0, 0);
  stageB(0, 0, 0);
  stageB(0, 1, 0);
  WAITVM(2);
  PBARRIER;

  for (int T = 0; T < NT; ++T) {
    const int cb = T & 1, nb = cb ^ 1;
    const bool st = (T + 1 < NT);
    LDA(cb);                 // A resident for the tile
    LDB(cb, 0, bfL);
    if (st) { stageA(nb, T + 1); stageB(nb, 0, T + 1); stageB(nb, 1, T + 1); }
    // p1: left B half
    MFMAKV(0, bfL);
    if (st) { WAITVM(6); } else { WAITVM(0); }   // retire B1(T)
    LDB(cb, 1, bfR);
    // p2: right B half
    MFMAKV(1, bfR);
    if (st) { WAITVM(2); }                       // retire A,B0(T+1); keep B1(T+1)
    PBARRIER;
  }

  // epilogue
  #pragma unroll
  for (int mf = 0; mf < 4; ++mf)
    #pragma unroll
    for (int nf = 0; nf < 4; ++nf)
      #pragma unroll
      for (int e = 0; e < 4; ++e) {
        int row = bm * 128 + (w >> 2) * 64 + mf * 16 + lh * 4 + e;
        int col = bn * 256 + bcol0 + nf * 16 + ln15;
        float v = acc[mf][nf][e];
        float pv = __shfl_xor(v, 1);
        int s = row & (Sc - 1), bb = row >> 10;
        if (col < 1024) {          // K + RoPE
          int hkv = col >> 7, d = col & 127;
          float2 cs = *(const float2*)(tbl + (size_t)(s * 64 + (d >> 1)) * 2);
          float o = (d & 1) ? (v * cs.x + pv * cs.y) : (v * cs.x - pv * cs.y);
          Krp[(((size_t)(bb * HKVc + hkv) * Sc + s) << 7) + d] = f2bf(o);
        } else {                   // V, sigma-permuted transpose
          int vc = col - 1024;
          int hkv = vc >> 7, d = vc & 127;
          int sl = s & 63;
          int sg = (sl & 32) | (((sl >> 2) & 3) << 3) | (((sl >> 4) & 1) << 2) | (sl & 3);
          Vtp[((size_t)(bb * HKVc + hkv) * Dc + d) * Sc + (s & ~63) + sg] = f2bf(v);
        }
      }
}

// ---------------- Flash attention (causal, GQA), swapped-QK^T, P in registers ----------------
// 4 waves x 32 q-rows (2 groups of 16). K/V fragment reads shared across both
// groups -> LDS read amplification halved vs 8-wave/16-row version.
__global__ __launch_bounds__(256, 2) void attn_k(const u16* __restrict__ Q, const u16* __restrict__ Kr,
                                                 const u16* __restrict__ Vt, u16* __restrict__ AO) {
  extern __shared__ char smem[];
  const int t = threadIdx.x, l = t & 63, w = t >> 6;   // w in 0..3
  const int qb = (int)gridDim.x - 1 - (int)blockIdx.x;   // big causal tiles first
  const int h = blockIdx.y, b = blockIdx.z;
  const int hkv = h >> 2;
  const int ln15 = l & 15, lh = l >> 4;
  const int NT = 2 * qb + 2;

  const u16* Kg0 = Kr + (size_t)(b * HKVc + hkv) * Sc * Dc;
  const u16* Vg0 = Vt + (size_t)(b * HKVc + hkv) * Dc * Sc;

  auto stageK = [&](int buf, int tt) {      // 64 rows x 128 d; wave stages 16 rows
    char* base = smem + buf * 16384 + w * 4096;
    #pragma unroll
    for (int i = 0; i < 4; ++i) {
      int row = w * 16 + i * 4 + (l >> 4);
      int c = l & 15;
      gload_lds16(Kg0 + (size_t)(tt * 64 + row) * Dc + ((c ^ (row & 7)) << 3), base + i * 1024);
    }
  };
  auto stageV = [&](int buf, int tt) {      // 128 d x 64 kv; wave stages 32 d-rows
    char* base = smem + 32768 + buf * 16384 + w * 4096;
    #pragma unroll
    for (int i = 0; i < 4; ++i) {
      int d = w * 32 + i * 8 + (l >> 3);
      int c = l & 7;
      gload_lds16(Vg0 + (size_t)d * Sc + tt * 64 + ((c ^ (d & 7)) << 3), base + i * 1024);
    }
  };

  // Q fragments: 2 groups of 16 q-rows per wave
  short8_t qf[2][4];
  #pragma unroll
  for (int g = 0; g < 2; ++g) {
    int q = qb * 128 + w * 32 + g * 16 + ln15;
    const u16* qp = Q + ((size_t)(b * Hc + h) * Sc + q) * Dc + lh * 8;
    #pragma unroll
    for (int ks = 0; ks < 4; ++ks) qf[g][ks] = *(const short8_t*)(qp + ks * 32);
  }
  SBAR;   // qf loads issued before staging (vmcnt ordering)

  f32x4 oacc[2][8];
  #pragma unroll
  for (int g = 0; g < 2; ++g)
    #pragma unroll
    for (int i = 0; i < 8; ++i) oacc[g][i] = f32x4{0.f, 0.f, 0.f, 0.f};
  float mrun[2] = {-1e30f, -1e30f}, lrun[2] = {0.f, 0.f};

  stageK(0, 0); stageV(0, 0);
  stageK(1, 1); stageV(1, 1);

  const int qmaxw = qb * 128 + w * 32 + 31;

  for (int T = 0; T < NT; ++T) {
    if (T < NT - 1) { WAITVM(8); } else { WAITVM(0); }
    PBARRIER;
    const char* Kb = smem + (T & 1) * 16384;
    const char* Vb = smem + 32768 + (T & 1) * 16384;

    if (T * 64 <= qmaxw) {     // both groups active together (32-aligned offsets)
      // S^T = K.Q^T per group; kf shared across groups
      f32x4 sf[2][4];
      #pragma unroll
      for (int fc = 0; fc < 4; ++fc) {
        sf[0][fc] = f32x4{0.f, 0.f, 0.f, 0.f};
        sf[1][fc] = f32x4{0.f, 0.f, 0.f, 0.f};
        int kvr = fc * 16 + ln15;
        #pragma unroll
        for (int ks = 0; ks < 4; ++ks) {
          int chunk = ks * 4 + lh;
          short8_t kf = *(const short8_t*)(Kb + kvr * 256 + ((chunk ^ (kvr & 7)) << 4));
          sf[0][fc] = __builtin_amdgcn_mfma_f32_16x16x32_bf16(kf, qf[0][ks], sf[0][fc], 0, 0, 0);
          sf[1][fc] = __builtin_amdgcn_mfma_f32_16x16x32_bf16(kf, qf[1][ks], sf[1][fc], 0, 0, 0);
        }
      }
      if (T * 64 + 63 > qb * 128 + w * 32) {   // diagonal overlap: mask kv > q per group
        #pragma unroll
        for (int g = 0; g < 2; ++g) {
          int qlane = qb * 128 + w * 32 + g * 16 + ln15;
          #pragma unroll
          for (int fc = 0; fc < 4; ++fc)
            #pragma unroll
            for (int j = 0; j < 4; ++j) {
              int kvg = T * 64 + fc * 16 + lh * 4 + j;
              if (kvg > qlane) sf[g][fc][j] = -1e30f;
            }
        }
      }
      // online softmax per group
      short8_t pa[2][2];
      #pragma unroll
      for (int g = 0; g < 2; ++g) {
        float mx = sf[g][0][0];
        #pragma unroll
        for (int fc = 0; fc < 4; ++fc)
          #pragma unroll
          for (int j = 0; j < 4; ++j) mx = fmaxf(mx, sf[g][fc][j]);
        mx = fmaxf(mx, __shfl_xor(mx, 16));
        mx = fmaxf(mx, __shfl_xor(mx, 32));
        float mnew = fmaxf(mrun[g], mx);
        float alpha = __expf(mrun[g] - mnew);
        mrun[g] = mnew;
        float rs = 0.f;
        #pragma unroll
        for (int fc = 0; fc < 4; ++fc)
          #pragma unroll
          for (int j = 0; j < 4; ++j) {
            float p = __expf(sf[g][fc][j] - mnew);
            sf[g][fc][j] = p;
            rs += p;
          }
        rs += __shfl_xor(rs, 16);
        rs += __shfl_xor(rs, 32);
        lrun[g] = lrun[g] * alpha + rs;
        float arow[4];
        #pragma unroll
        for (int j = 0; j < 4; ++j) arow[j] = __shfl(alpha, (l & 48) | (lh * 4 + j));
        #pragma unroll
        for (int fd = 0; fd < 8; ++fd)
          #pragma unroll
          for (int j = 0; j < 4; ++j) oacc[g][fd][j] *= arow[j];
        #pragma unroll
        for (int ks = 0; ks < 2; ++ks)
          #pragma unroll
          for (int b2 = 0; b2 < 2; ++b2)
            #pragma unroll
            for (int j = 0; j < 4; ++j) pa[g][ks][b2 * 4 + j] = (short)f2bf(sf[g][ks * 2 + b2][j]);
      }
      // PV: vf shared across groups
      #pragma unroll
      for (int fd = 0; fd < 8; ++fd) {
        int dcol = fd * 16 + ln15;
        #pragma unroll
        for (int ks = 0; ks < 2; ++ks) {
          int chunk = ks * 4 + lh;
          short8_t vf = *(const short8_t*)(Vb + dcol * 128 + ((chunk ^ (dcol & 7)) << 4));
          oacc[0][fd] = __builtin_amdgcn_mfma_f32_16x16x32_bf16(pa[0][ks], vf, oacc[0][fd], 0, 0, 0);
          oacc[1][fd] = __builtin_amdgcn_mfma_f32_16x16x32_bf16(pa[1][ks], vf, oacc[1][fd], 0, 0, 0);
        }
      }
    }
    PBARRIER;
    if (T + 2 < NT) { stageK(T & 1, T + 2); stageV(T & 1, T + 2); }
  }

  // epilogue per group: O /= l, write [b][s][h*128+d]
  #pragma unroll
  for (int g = 0; g < 2; ++g) {
    float linv[4];
    #pragma unroll
    for (int j = 0; j < 4; ++j) linv[j] = 1.f / __shfl(lrun[g], (l & 48) | (lh * 4 + j));
    #pragma unroll
    for (int j = 0; j < 4; ++j) {
      int q = qb * 128 + w * 32 + g * 16 + lh * 4 + j;
      u16* op = AO + (size_t)(b * Sc + q) * DIMc + h * Dc + ln15;
      #pragma unroll
      for (int fd = 0; fd < 8; ++fd) op[fd * 16] = f2bf(oacc[g][fd][j] * linv[j]);
    }
  }
}

extern "C" void kernel_launch(void* const* d_in, const int* in_sizes, int n_in,
                              void* d_out, int out_size, void* d_ws, size_t ws_size,
                              hipStream_t stream) {
  const float* x  = (const float*)d_in[0];
  const float* wq = (const float*)d_in[1];
  const float* wk = (const float*)d_in[2];
  const float* wv = (const float*)d_in[3];
  const float* wo = (const float*)d_in[4];
  float* out = (float*)d_out;

  char* ws = (char*)d_ws;
  size_t off = 0;
  auto alloc = [&](size_t bytes) -> char* {
    char* p = ws + off;
    off += (bytes + 255) & ~(size_t)255;
    return p;
  };
  float* tbl  = (float*)alloc((size_t)Sc * 64 * 2 * 4);
  u16* xb    = (u16*)alloc((size_t)BS * DIMc * 2);     // x bf16; later reused as AO
  u16* wqT   = (u16*)alloc((size_t)4096 * 4096 * 2);   // wqT; later woT
  u16* wkvT  = (u16*)alloc((size_t)2048 * 4096 * 2);   // [wkT ; wvT]
  u16* Qb    = (u16*)alloc((size_t)BS * 4096 * 2);     // roped Q in [b][h][s][d]
  u16* Krp   = (u16*)alloc((size_t)BS * 1024 * 2);     // roped K in [b][hkv][s][d]
  u16* Vtp   = (u16*)alloc((size_t)BS * 1024 * 2);     // V in [b][hkv][d][sigma(s)]
  u16* AO = xb;    // alias: xb dead after K/V GEMM
  u16* woT = wqT;  // alias: wqT dead after Q GEMM

  rope_table_k<<<(Sc * 64) / 256, 256, 0, stream>>>(tbl);
  f32_to_bf16_k<<<(BS * DIMc / 4) / 256, 256, 0, stream>>>(x, xb, BS * DIMc / 4);

  transpose_w_k<<<dim3(64, 64), 256, 0, stream>>>(wq, wqT, 4096, 4096);
  gemm256<2><<<256, 512, 131072, stream>>>(xb, wqT, Qb, tbl, 4096, 4096, 4096);  // Q + RoPE + relayout

  transpose_w_k<<<dim3(16, 64), 256, 0, stream>>>(wk, wkvT, 4096, 1024);
  transpose_w_k<<<dim3(16, 64), 256, 0, stream>>>(wv, wkvT + (size_t)1024 * 4096, 4096, 1024);
  gemm_kv<<<256, 512, 98304, stream>>>(xb, wkvT, Krp, Vtp, tbl);                 // K+RoPE, V+sigma-transpose

  attn_k<<<dim3(8, Hc, Bc), 256, 65536, stream>>>(Qb, Krp, Vtp, AO);

  transpose_w_k<<<dim3(64, 64), 256, 0, stream>>>(wo, woT, 4096, 4096);
  gemm256<1><<<256, 512, 131072, stream>>>(AO, woT, out, tbl, 4096, 4096, 4096);
}

// Round 16
// 452.226 us; speedup vs baseline: 1.0630x; 1.0311x over previous
//
#include <hip/hip_runtime.h>

typedef unsigned short u16;
typedef unsigned int u32;
typedef __attribute__((ext_vector_type(8))) short short8_t;  // 8 bf16 (4 VGPRs)
typedef __attribute__((ext_vector_type(4))) float f32x4;

static constexpr int Bc = 4, Sc = 1024, Hc = 32, HKVc = 8, Dc = 128;
static constexpr int BS = Bc * Sc;     // 4096 rows
static constexpr int DIMc = 4096;

__device__ __forceinline__ u16 f2bf(float f) {
  u32 u = __float_as_uint(f);
  u32 r = (u + 0x7fffu + ((u >> 16) & 1u)) >> 16;  // RNE
  return (u16)r;
}
__device__ __forceinline__ float bf2f(u16 u) {
  return __uint_as_float(((u32)u) << 16);
}
__device__ __forceinline__ void gload_lds16(const void* g, void* l) {
  __builtin_amdgcn_global_load_lds((const __attribute__((address_space(1))) void*)g,
                                   (__attribute__((address_space(3))) void*)l, 16, 0, 0);
}

#define SBAR __builtin_amdgcn_sched_barrier(0)
#define PBARRIER do { SBAR; __builtin_amdgcn_s_barrier(); SBAR; } while (0)
#define WAITVM(N) asm volatile("s_waitcnt vmcnt(" #N ")" ::: "memory")

// ---------------- shared transpose body: W(K,N) fp32 -> WT(N,K) bf16, 64x64 tile ----------------
__device__ __forceinline__ void transpose_tile(const float* __restrict__ W, u16* __restrict__ WT,
                                               int Kdim, int Ndim, int n0, int k0, int t,
                                               float* tile /* 64*65 floats */) {
  #pragma unroll
  for (int p = 0; p < 4; ++p) {
    int idx = p * 256 + t;           // 1024 float4 chunks
    int r = idx >> 4, c = (idx & 15) * 4;
    float4 v = *(const float4*)(W + (size_t)(k0 + r) * Ndim + n0 + c);
    tile[r * 65 + c + 0] = v.x;
    tile[r * 65 + c + 1] = v.y;
    tile[r * 65 + c + 2] = v.z;
    tile[r * 65 + c + 3] = v.w;
  }
  __syncthreads();
  #pragma unroll
  for (int p = 0; p < 2; ++p) {
    int idx = p * 256 + t;           // 512 chunks of 8 bf16
    int n = idx >> 3, c = (idx & 7) * 8;
    alignas(16) u16 o[8];
    #pragma unroll
    for (int i = 0; i < 8; ++i) o[i] = f2bf(tile[(c + i) * 65 + n]);
    *(uint4*)(WT + (size_t)(n0 + n) * Kdim + k0 + c) = *(const uint4*)o;
  }
}

// ---------------- fused preprocessing: x-cvt | wq^T | wk^T | wv^T | rope table ----------------
// block ranges: [0,4096) x cvt (4 float4/thread); [4096,8192) wq; [8192,9216) wk;
// [9216,10240) wv; [10240,10496) rope table.
__global__ __launch_bounds__(256) void prep_k(const float* __restrict__ x, u16* __restrict__ xb,
                                              const float* __restrict__ wq, u16* __restrict__ wqT,
                                              const float* __restrict__ wk, const float* __restrict__ wv,
                                              u16* __restrict__ wkvT, float* __restrict__ tbl) {
  __shared__ float tile[64 * 65];
  const int id = blockIdx.x, t = threadIdx.x;
  if (id < 4096) {
    // x fp32 -> bf16, 4096 float4 per block
    #pragma unroll
    for (int p = 0; p < 4; ++p) {
      size_t i = (size_t)id * 1024 + p * 256 + t;
      float4 v = *(const float4*)(x + i * 4);
      uint2 pk;
      pk.x = (u32)f2bf(v.x) | ((u32)f2bf(v.y) << 16);
      pk.y = (u32)f2bf(v.z) | ((u32)f2bf(v.w) << 16);
      *(uint2*)(xb + i * 4) = pk;
    }
  } else if (id < 8192) {
    int b = id - 4096;
    transpose_tile(wq, wqT, 4096, 4096, (b & 63) * 64, (b >> 6) * 64, t, tile);
  } else if (id < 9216) {
    int b = id - 8192;
    transpose_tile(wk, wkvT, 4096, 1024, (b & 15) * 64, (b >> 4) * 64, t, tile);
  } else if (id < 10240) {
    int b = id - 9216;
    transpose_tile(wv, wkvT + (size_t)1024 * 4096, 4096, 1024, (b & 15) * 64, (b >> 4) * 64, t, tile);
  } else {
    int i = (id - 10240) * 256 + t;     // 1024*64 entries
    int s = i >> 6, fi = i & 63;
    float freq = powf(10000.f, -(float)fi / 64.f);
    float ang = (float)s * freq;
    float sv, cv;
    sincosf(ang, &sv, &cv);
    tbl[2 * i] = cv;
    tbl[2 * i + 1] = sv;
  }
}

// ---------------- standalone W transpose (wo) ----------------
__global__ __launch_bounds__(256) void transpose_w_k(const float* __restrict__ W, u16* __restrict__ WT,
                                                     int Kdim, int Ndim) {
  __shared__ float tile[64 * 65];
  transpose_tile(W, WT, Kdim, Ndim, blockIdx.x * 64, blockIdx.y * 64, threadIdx.x, tile);
}

// ---------------- 256^2-tile GEMM, m201-faithful 4-phase schedule (R15 best) ----------------
// MODE 1: f32 C row-major; MODE 2: bf16 + fused RoPE + relayout to Q[b][h][s][d].
#define MFMAQ(QI, AF, BF)                                                                \
  do {                                                                                   \
    __builtin_amdgcn_s_setprio(1);                                                       \
    _Pragma("unroll") for (int mf = 0; mf < 4; ++mf)                                     \
      _Pragma("unroll") for (int nf = 0; nf < 2; ++nf)                                   \
        _Pragma("unroll") for (int kk = 0; kk < 2; ++kk)                                 \
          acc[QI][mf][nf] = __builtin_amdgcn_mfma_f32_16x16x32_bf16(                     \
              AF[mf][kk], BF[nf][kk], acc[QI][mf][nf], 0, 0, 0);                         \
    __builtin_amdgcn_s_setprio(0);                                                       \
  } while (0)

template <int MODE>
__global__ __launch_bounds__(512, 2) void gemm256(const u16* __restrict__ A, const u16* __restrict__ BT,
                                                  void* __restrict__ Cv, const float* __restrict__ tbl,
                                                  int M, int N, int K) {
  extern __shared__ char smem[];   // 131072 B
  const int t = threadIdx.x, l = t & 63, w = t >> 6;
  const int ln15 = l & 15, lh = l >> 4;
  const int NT = K >> 6;

  int id = blockIdx.x;
  int nwg = gridDim.x;
  int swz = ((nwg & 7) == 0) ? ((id & 7) * (nwg >> 3) + (id >> 3)) : id;
  const int nbn = N >> 8;
  const int bm = swz / nbn, bn = swz % nbn;

  const u16* Ag = A + (size_t)bm * 256 * K;
  const u16* Bg = BT + (size_t)bn * 256 * K;

  f32x4 acc[4][4][2];
  #pragma unroll
  for (int q = 0; q < 4; ++q)
    #pragma unroll
    for (int mf = 0; mf < 4; ++mf)
      #pragma unroll
      for (int nf = 0; nf < 2; ++nf) acc[q][mf][nf] = f32x4{0.f, 0.f, 0.f, 0.f};
  short8_t af[4][2], af2[4][2], bfB0[2][2], bfB1[2][2];

  const int srow = (l >> 3);
  const int sck  = (l & 7) ^ srow;
  auto stageA = [&](char* bufbase, int h, int tt) {
    char* lb = bufbase + h * 16384 + w * 1024;
    const u16* g = Ag + (size_t)(h * 128 + w * 8 + srow) * K + tt * 64 + (sck << 3);
    gload_lds16(g, lb);
    gload_lds16(g + (size_t)64 * K, lb + 8192);
  };
  auto stageB = [&](char* bufbase, int h, int tt) {
    char* lb = bufbase + 32768 + h * 16384 + w * 1024;
    const u16* g = Bg + (size_t)(h * 128 + w * 8 + srow) * K + tt * 64 + (sck << 3);
    gload_lds16(g, lb);
    gload_lds16(g + (size_t)64 * K, lb + 8192);
  };
  const int arow = (w >> 2) * 64 + ln15;
  const int brow = (w & 3) * 32 + ln15;
  const int rsw = ln15 & 7;
  auto LDA = [&](const char* cb, int qm, short8_t (&dst)[4][2]) {
    #pragma unroll
    for (int mf = 0; mf < 4; ++mf)
      #pragma unroll
      for (int kk = 0; kk < 2; ++kk)
        dst[mf][kk] = *(const short8_t*)(cb + qm * 16384 + (arow + mf * 16) * 128 +
                                         (((kk * 4 + lh) ^ rsw) << 4));
  };
  auto LDB = [&](const char* cb, int qn, short8_t (&dst)[2][2]) {
    #pragma unroll
    for (int nf = 0; nf < 2; ++nf)
      #pragma unroll
      for (int kk = 0; kk < 2; ++kk)
        dst[nf][kk] = *(const short8_t*)(cb + 32768 + qn * 16384 + (brow + nf * 16) * 128 +
                                         (((kk * 4 + lh) ^ rsw) << 4));
  };

  // ---- prologue: tile 0 fully + A0,B0,A1 of tile 1 (14 loads); retire tile 0 ----
  {
    char* b0 = smem;
    char* b1 = smem + 65536;
    stageA(b0, 0, 0); stageB(b0, 0, 0); stageA(b0, 1, 0); stageB(b0, 1, 0);
    stageA(b1, 0, 1); stageB(b1, 0, 1); stageA(b1, 1, 1);
  }
  WAITVM(6);    // tile 0 retired; {A0,B0,A1}(1) in flight
  PBARRIER;

  for (int T = 0; T < NT; ++T) {
    char* cb = smem + (T & 1) * 65536;
    char* nb = smem + ((T & 1) ^ 1) * 65536;
    const bool s1 = (T + 1 < NT), s2 = (T + 2 < NT);
    // ph1: Q00 reads A0(8)+B0(4); stage B1(T+1) -> nb (nb.B1 last read ph3(T-1))
    LDA(cb, 0, af); LDB(cb, 0, bfB0);
    if (s1) stageB(nb, 1, T + 1);
    PBARRIER;
    MFMAQ(0, af, bfB0);
    // ph2: Q10 reads A1(8); stage A0(T+2) -> cb (cb.A0 freed after ph1)
    LDA(cb, 1, af2);
    if (s2) stageA(cb, 0, T + 2);
    PBARRIER;
    MFMAQ(1, af2, bfB0);
    // ph3: Q11 reads B1(4); stage B0(T+2) -> cb (cb.B0 freed after ph1/2)
    LDB(cb, 1, bfB1);
    if (s2) stageB(cb, 0, T + 2);
    PBARRIER;
    MFMAQ(2, af2, bfB1);
    // ph4: Q01 no reads; stage A1(T+2) -> cb (freed after ph3); counted vmcnt
    if (s2) { stageA(cb, 1, T + 2); WAITVM(6); }
    else if (s1) { WAITVM(0); }       // tail: drain before final tile
    PBARRIER;
    MFMAQ(3, af, bfB1);
  }

  // ---- epilogue ----
  const int rw = (w >> 2) * 64, cw = (w & 3) * 32;
  #pragma unroll
  for (int qi = 0; qi < 4; ++qi) {
    const int qm = (qi == 1 || qi == 2) ? 1 : 0;
    const int qn = (qi >= 2) ? 1 : 0;
    #pragma unroll
    for (int mf = 0; mf < 4; ++mf)
      #pragma unroll
      for (int nf = 0; nf < 2; ++nf)
        #pragma unroll
        for (int e = 0; e < 4; ++e) {
          int row = bm * 256 + qm * 128 + rw + mf * 16 + lh * 4 + e;
          int col = bn * 256 + qn * 128 + cw + nf * 16 + ln15;
          float v = acc[qi][mf][nf][e];
          if (MODE == 2) {
            float pv = __shfl_xor(v, 1);        // partner holds col^1 (same row)
            int d = col & 127, hh = col >> 7;
            int s = row & (Sc - 1), bb = row >> 10;
            float2 cs = *(const float2*)(tbl + (size_t)(s * 64 + (d >> 1)) * 2);
            float o = (d & 1) ? (v * cs.x + pv * cs.y) : (v * cs.x - pv * cs.y);
            o *= 0.08838834764831845f;
            ((u16*)Cv)[(((size_t)(bb * Hc + hh) * Sc + s) << 7) + d] = f2bf(o);
          } else {
            size_t idx = (size_t)row * N + col;
            ((float*)Cv)[idx] = v;
          }
        }
  }
}

// ---------------- Fused K+V projection GEMM, BM=128 x BN=256 ----------------
#define MFMAKV(PH, BF)                                                                   \
  do {                                                                                   \
    __builtin_amdgcn_s_setprio(1);                                                       \
    _Pragma("unroll") for (int mf = 0; mf < 4; ++mf)                                     \
      _Pragma("unroll") for (int nf = 0; nf < 2; ++nf)                                   \
        _Pragma("unroll") for (int kk = 0; kk < 2; ++kk)                                 \
          acc[mf][(PH) * 2 + nf] = __builtin_amdgcn_mfma_f32_16x16x32_bf16(              \
              af[mf][kk], BF[nf][kk], acc[mf][(PH) * 2 + nf], 0, 0, 0);                  \
    __builtin_amdgcn_s_setprio(0);                                                       \
  } while (0)

__global__ __launch_bounds__(512, 1) void gemm_kv(const u16* __restrict__ A, const u16* __restrict__ BT,
                                                  u16* __restrict__ Krp, u16* __restrict__ Vtp,
                                                  const float* __restrict__ tbl) {
  extern __shared__ char smem[];   // A dbuf 2x16KB @0 | B dbuf 2x32KB @32768 = 98304 B
  const int t = threadIdx.x, l = t & 63, w = t >> 6;
  const int ln15 = l & 15, lh = l >> 4;
  const int K = 4096, NT = 64;

  int id = blockIdx.x;
  int swz = (id & 7) * 32 + (id >> 3);      // 256 blocks, XCD-bijective
  const int bm = swz >> 3, bn = swz & 7;    // 32 x 8

  const u16* Ag = A + (size_t)bm * 128 * K;
  const u16* Bg = BT + (size_t)bn * 256 * K;

  f32x4 acc[4][4];
  #pragma unroll
  for (int mf = 0; mf < 4; ++mf)
    #pragma unroll
    for (int nf = 0; nf < 4; ++nf) acc[mf][nf] = f32x4{0.f, 0.f, 0.f, 0.f};
  short8_t af[4][2], bfL[2][2], bfR[2][2];

  const int srow = (l >> 3);
  const int sck  = (l & 7) ^ srow;
  auto stageA = [&](int buf, int tt) {          // A tile = 128 rows x 64 K = 16KB
    char* lb = smem + buf * 16384 + w * 1024;
    const u16* g = Ag + (size_t)(w * 8 + srow) * K + tt * 64 + (sck << 3);
    gload_lds16(g, lb);
    gload_lds16(g + (size_t)64 * K, lb + 8192);
  };
  auto stageB = [&](int buf, int h, int tt) {   // one B half = 128 rows x 64 K = 16KB
    char* lb = smem + 32768 + buf * 32768 + h * 16384 + w * 1024;
    const u16* g = Bg + (size_t)(h * 128 + w * 8 + srow) * K + tt * 64 + (sck << 3);
    gload_lds16(g, lb);
    gload_lds16(g + (size_t)64 * K, lb + 8192);
  };
  const int arow = (w >> 2) * 64 + ln15;        // 0..127 within A tile
  const int bcol0 = (w & 3) * 64;               // wave's B col group (4 nf x 16)
  const int rsw = ln15 & 7;
  auto LDA = [&](int buf) {
    #pragma unroll
    for (int mf = 0; mf < 4; ++mf)
      #pragma unroll
      for (int kk = 0; kk < 2; ++kk)
        af[mf][kk] = *(const short8_t*)(smem + buf * 16384 + (arow + mf * 16) * 128 +
                                        (((kk * 4 + lh) ^ rsw) << 4));
  };
  auto LDB = [&](int buf, int half, short8_t (&dst)[2][2]) {
    #pragma unroll
    for (int nf = 0; nf < 2; ++nf)
      #pragma unroll
      for (int kk = 0; kk < 2; ++kk) {
        int brow = bcol0 + (half * 2 + nf) * 16 + ln15;   // 0..255
        dst[nf][kk] = *(const short8_t*)(smem + 32768 + buf * 32768 + brow * 128 +
                                         (((kk * 4 + lh) ^ rsw) << 4));
      }
  };

  // prologue: stage tile 0 (A, B0, B1); retire A,B0 (B1 stays in flight)
  stageA(0, 0);
  stageB(0, 0, 0);
  stageB(0, 1, 0);
  WAITVM(2);
  PBARRIER;

  for (int T = 0; T < NT; ++T) {
    const int cb = T & 1, nb = cb ^ 1;
    const bool st = (T + 1 < NT);
    LDA(cb);                 // A resident for the tile
    LDB(cb, 0, bfL);
    if (st) { stageA(nb, T + 1); stageB(nb, 0, T + 1); stageB(nb, 1, T + 1); }
    // p1: left B half
    MFMAKV(0, bfL);
    if (st) { WAITVM(6); } else { WAITVM(0); }   // retire B1(T)
    LDB(cb, 1, bfR);
    // p2: right B half
    MFMAKV(1, bfR);
    if (st) { WAITVM(2); }                       // retire A,B0(T+1); keep B1(T+1)
    PBARRIER;
  }

  // epilogue
  #pragma unroll
  for (int mf = 0; mf < 4; ++mf)
    #pragma unroll
    for (int nf = 0; nf < 4; ++nf)
      #pragma unroll
      for (int e = 0; e < 4; ++e) {
        int row = bm * 128 + (w >> 2) * 64 + mf * 16 + lh * 4 + e;
        int col = bn * 256 + bcol0 + nf * 16 + ln15;
        float v = acc[mf][nf][e];
        float pv = __shfl_xor(v, 1);
        int s = row & (Sc - 1), bb = row >> 10;
        if (col < 1024) {          // K + RoPE
          int hkv = col >> 7, d = col & 127;
          float2 cs = *(const float2*)(tbl + (size_t)(s * 64 + (d >> 1)) * 2);
          float o = (d & 1) ? (v * cs.x + pv * cs.y) : (v * cs.x - pv * cs.y);
          Krp[(((size_t)(bb * HKVc + hkv) * Sc + s) << 7) + d] = f2bf(o);
        } else {                   // V, sigma-permuted transpose
          int vc = col - 1024;
          int hkv = vc >> 7, d = vc & 127;
          int sl = s & 63;
          int sg = (sl & 32) | (((sl >> 2) & 3) << 3) | (((sl >> 4) & 1) << 2) | (sl & 3);
          Vtp[((size_t)(bb * HKVc + hkv) * Dc + d) * Sc + (s & ~63) + sg] = f2bf(v);
        }
      }
}

// ---------------- Flash attention (causal, GQA), swapped-QK^T, P in registers ----------------
// 4 waves x 32 q-rows (2 groups of 16). K/V fragment reads shared across both
// groups -> LDS read amplification halved vs 8-wave/16-row version.
__global__ __launch_bounds__(256, 2) void attn_k(const u16* __restrict__ Q, const u16* __restrict__ Kr,
                                                 const u16* __restrict__ Vt, u16* __restrict__ AO) {
  extern __shared__ char smem[];
  const int t = threadIdx.x, l = t & 63, w = t >> 6;   // w in 0..3
  const int qb = (int)gridDim.x - 1 - (int)blockIdx.x;   // big causal tiles first
  const int h = blockIdx.y, b = blockIdx.z;
  const int hkv = h >> 2;
  const int ln15 = l & 15, lh = l >> 4;
  const int NT = 2 * qb + 2;

  const u16* Kg0 = Kr + (size_t)(b * HKVc + hkv) * Sc * Dc;
  const u16* Vg0 = Vt + (size_t)(b * HKVc + hkv) * Dc * Sc;

  auto stageK = [&](int buf, int tt) {      // 64 rows x 128 d; wave stages 16 rows
    char* base = smem + buf * 16384 + w * 4096;
    #pragma unroll
    for (int i = 0; i < 4; ++i) {
      int row = w * 16 + i * 4 + (l >> 4);
      int c = l & 15;
      gload_lds16(Kg0 + (size_t)(tt * 64 + row) * Dc + ((c ^ (row & 7)) << 3), base + i * 1024);
    }
  };
  auto stageV = [&](int buf, int tt) {      // 128 d x 64 kv; wave stages 32 d-rows
    char* base = smem + 32768 + buf * 16384 + w * 4096;
    #pragma unroll
    for (int i = 0; i < 4; ++i) {
      int d = w * 32 + i * 8 + (l >> 3);
      int c = l & 7;
      gload_lds16(Vg0 + (size_t)d * Sc + tt * 64 + ((c ^ (d & 7)) << 3), base + i * 1024);
    }
  };

  // Q fragments: 2 groups of 16 q-rows per wave
  short8_t qf[2][4];
  #pragma unroll
  for (int g = 0; g < 2; ++g) {
    int q = qb * 128 + w * 32 + g * 16 + ln15;
    const u16* qp = Q + ((size_t)(b * Hc + h) * Sc + q) * Dc + lh * 8;
    #pragma unroll
    for (int ks = 0; ks < 4; ++ks) qf[g][ks] = *(const short8_t*)(qp + ks * 32);
  }
  SBAR;   // qf loads issued before staging (vmcnt ordering)

  f32x4 oacc[2][8];
  #pragma unroll
  for (int g = 0; g < 2; ++g)
    #pragma unroll
    for (int i = 0; i < 8; ++i) oacc[g][i] = f32x4{0.f, 0.f, 0.f, 0.f};
  float mrun[2] = {-1e30f, -1e30f}, lrun[2] = {0.f, 0.f};

  stageK(0, 0); stageV(0, 0);
  stageK(1, 1); stageV(1, 1);

  const int qmaxw = qb * 128 + w * 32 + 31;

  for (int T = 0; T < NT; ++T) {
    if (T < NT - 1) { WAITVM(8); } else { WAITVM(0); }
    PBARRIER;
    const char* Kb = smem + (T & 1) * 16384;
    const char* Vb = smem + 32768 + (T & 1) * 16384;

    if (T * 64 <= qmaxw) {     // both groups active together (32-aligned offsets)
      f32x4 sf[2][4];
      #pragma unroll
      for (int fc = 0; fc < 4; ++fc) {
        sf[0][fc] = f32x4{0.f, 0.f, 0.f, 0.f};
        sf[1][fc] = f32x4{0.f, 0.f, 0.f, 0.f};
        int kvr = fc * 16 + ln15;
        #pragma unroll
        for (int ks = 0; ks < 4; ++ks) {
          int chunk = ks * 4 + lh;
          short8_t kf = *(const short8_t*)(Kb + kvr * 256 + ((chunk ^ (kvr & 7)) << 4));
          sf[0][fc] = __builtin_amdgcn_mfma_f32_16x16x32_bf16(kf, qf[0][ks], sf[0][fc], 0, 0, 0);
          sf[1][fc] = __builtin_amdgcn_mfma_f32_16x16x32_bf16(kf, qf[1][ks], sf[1][fc], 0, 0, 0);
        }
      }
      if (T * 64 + 63 > qb * 128 + w * 32) {   // diagonal overlap: mask kv > q per group
        #pragma unroll
        for (int g = 0; g < 2; ++g) {
          int qlane = qb * 128 + w * 32 + g * 16 + ln15;
          #pragma unroll
          for (int fc = 0; fc < 4; ++fc)
            #pragma unroll
            for (int j = 0; j < 4; ++j) {
              int kvg = T * 64 + fc * 16 + lh * 4 + j;
              if (kvg > qlane) sf[g][fc][j] = -1e30f;
            }
        }
      }
      short8_t pa[2][2];
      #pragma unroll
      for (int g = 0; g < 2; ++g) {
        float mx = sf[g][0][0];
        #pragma unroll
        for (int fc = 0; fc < 4; ++fc)
          #pragma unroll
          for (int j = 0; j < 4; ++j) mx = fmaxf(mx, sf[g][fc][j]);
        mx = fmaxf(mx, __shfl_xor(mx, 16));
        mx = fmaxf(mx, __shfl_xor(mx, 32));
        float mnew = fmaxf(mrun[g], mx);
        float alpha = __expf(mrun[g] - mnew);
        mrun[g] = mnew;
        float rs = 0.f;
        #pragma unroll
        for (int fc = 0; fc < 4; ++fc)
          #pragma unroll
          for (int j = 0; j < 4; ++j) {
            float p = __expf(sf[g][fc][j] - mnew);
            sf[g][fc][j] = p;
            rs += p;
          }
        rs += __shfl_xor(rs, 16);
        rs += __shfl_xor(rs, 32);
        lrun[g] = lrun[g] * alpha + rs;
        float arow[4];
        #pragma unroll
        for (int j = 0; j < 4; ++j) arow[j] = __shfl(alpha, (l & 48) | (lh * 4 + j));
        #pragma unroll
        for (int fd = 0; fd < 8; ++fd)
          #pragma unroll
          for (int j = 0; j < 4; ++j) oacc[g][fd][j] *= arow[j];
        #pragma unroll
        for (int ks = 0; ks < 2; ++ks)
          #pragma unroll
          for (int b2 = 0; b2 < 2; ++b2)
            #pragma unroll
            for (int j = 0; j < 4; ++j) pa[g][ks][b2 * 4 + j] = (short)f2bf(sf[g][ks * 2 + b2][j]);
      }
      #pragma unroll
      for (int fd = 0; fd < 8; ++fd) {
        int dcol = fd * 16 + ln15;
        #pragma unroll
        for (int ks = 0; ks < 2; ++ks) {
          int chunk = ks * 4 + lh;
          short8_t vf = *(const short8_t*)(Vb + dcol * 128 + ((chunk ^ (dcol & 7)) << 4));
          oacc[0][fd] = __builtin_amdgcn_mfma_f32_16x16x32_bf16(pa[0][ks], vf, oacc[0][fd], 0, 0, 0);
          oacc[1][fd] = __builtin_amdgcn_mfma_f32_16x16x32_bf16(pa[1][ks], vf, oacc[1][fd], 0, 0, 0);
        }
      }
    }
    PBARRIER;
    if (T + 2 < NT) { stageK(T & 1, T + 2); stageV(T & 1, T + 2); }
  }

  // epilogue per group: O /= l, write [b][s][h*128+d]
  #pragma unroll
  for (int g = 0; g < 2; ++g) {
    float linv[4];
    #pragma unroll
    for (int j = 0; j < 4; ++j) linv[j] = 1.f / __shfl(lrun[g], (l & 48) | (lh * 4 + j));
    #pragma unroll
    for (int j = 0; j < 4; ++j) {
      int q = qb * 128 + w * 32 + g * 16 + lh * 4 + j;
      u16* op = AO + (size_t)(b * Sc + q) * DIMc + h * Dc + ln15;
      #pragma unroll
      for (int fd = 0; fd < 8; ++fd) op[fd * 16] = f2bf(oacc[g][fd][j] * linv[j]);
    }
  }
}

extern "C" void kernel_launch(void* const* d_in, const int* in_sizes, int n_in,
                              void* d_out, int out_size, void* d_ws, size_t ws_size,
                              hipStream_t stream) {
  const float* x  = (const float*)d_in[0];
  const float* wq = (const float*)d_in[1];
  const float* wk = (const float*)d_in[2];
  const float* wv = (const float*)d_in[3];
  const float* wo = (const float*)d_in[4];
  float* out = (float*)d_out;

  char* ws = (char*)d_ws;
  size_t off = 0;
  auto alloc = [&](size_t bytes) -> char* {
    char* p = ws + off;
    off += (bytes + 255) & ~(size_t)255;
    return p;
  };
  float* tbl  = (float*)alloc((size_t)Sc * 64 * 2 * 4);
  u16* xb    = (u16*)alloc((size_t)BS * DIMc * 2);     // x bf16; later reused as AO
  u16* wqT   = (u16*)alloc((size_t)4096 * 4096 * 2);   // wqT; later woT
  u16* wkvT  = (u16*)alloc((size_t)2048 * 4096 * 2);   // [wkT ; wvT]
  u16* Qb    = (u16*)alloc((size_t)BS * 4096 * 2);     // roped Q in [b][h][s][d]
  u16* Krp   = (u16*)alloc((size_t)BS * 1024 * 2);     // roped K in [b][hkv][s][d]
  u16* Vtp   = (u16*)alloc((size_t)BS * 1024 * 2);     // V in [b][hkv][d][sigma(s)]
  u16* AO = xb;    // alias: xb dead after K/V GEMM
  u16* woT = wqT;  // alias: wqT dead after Q GEMM

  // fused preprocessing: x cvt + wq/wk/wv transposes + rope table (one launch)
  prep_k<<<10496, 256, 0, stream>>>(x, xb, wq, wqT, wk, wv, wkvT, tbl);

  gemm256<2><<<256, 512, 131072, stream>>>(xb, wqT, Qb, tbl, 4096, 4096, 4096);  // Q + RoPE + relayout

  transpose_w_k<<<dim3(64, 64), 256, 0, stream>>>(wo, woT, 4096, 4096);          // wqT dead now

  gemm_kv<<<256, 512, 98304, stream>>>(xb, wkvT, Krp, Vtp, tbl);                 // K+RoPE, V+sigma-transpose

  attn_k<<<dim3(8, Hc, Bc), 256, 65536, stream>>>(Qb, Krp, Vtp, AO);

  gemm256<1><<<256, 512, 131072, stream>>>(AO, woT, out, tbl, 4096, 4096, 4096);
}